// Round 14
// baseline (1006.588 us; speedup 1.0000x reference)
//
#include <hip/hip_runtime.h>
#include <hip/hip_bf16.h>
#include <math.h>

// Problem constants
#define B_    64
#define T_    13
#define N_    325
#define H_    64
#define C_    4
#define L_    2
#define S_    4
#define P_    12
#define KCP   4            // checkpoints [4,7,10,13]
#define M_    (B_*N_)      // 20800 (= 650*32 exactly)
#define ADJLD 1300         // leading dim of combined adjacency inputs
#define NNZCAP 64          // max nonzeros per adjacency row (3% density -> mean ~10)
#define WPITCH 72          // ushort pitch, 64-k transposed W tiles
#define RPITCH 264         // ushort pitch, 256-k reduce tile and Mt rows

typedef short bfrag __attribute__((ext_vector_type(8)));   // 8 bf16 = 4 VGPRs
typedef float f32x4 __attribute__((ext_vector_type(4)));

#define FMA16 \
  acc[0][0]+=a0*b0; acc[0][1]+=a0*b1; acc[0][2]+=a0*b2; acc[0][3]+=a0*b3; \
  acc[1][0]+=a1*b0; acc[1][1]+=a1*b1; acc[1][2]+=a1*b2; acc[1][3]+=a1*b3; \
  acc[2][0]+=a2*b0; acc[2][1]+=a2*b1; acc[2][2]+=a2*b2; acc[2][3]+=a2*b3; \
  acc[3][0]+=a3*b0; acc[3][1]+=a3*b1; acc[3][2]+=a3*b2; acc[3][3]+=a3*b3;

__device__ __forceinline__ void fma4(float4& a, float s, float4 x) {
    a.x += s * x.x; a.y += s * x.y; a.z += s * x.z; a.w += s * x.w;
}
// bf16 pack (RNE) / unpack helpers
__device__ __forceinline__ ushort bf_rne(float f) {
    unsigned u = __float_as_uint(f);
    return (ushort)((u + 0x7fffu + ((u >> 16) & 1u)) >> 16);
}
__device__ __forceinline__ uint2 pack_bf4(float4 v) {
    unsigned a = __float_as_uint(v.x), b = __float_as_uint(v.y);
    unsigned c = __float_as_uint(v.z), d = __float_as_uint(v.w);
    a = (a + 0x7fffu + ((a >> 16) & 1u)) >> 16;
    b = (b + 0x7fffu + ((b >> 16) & 1u)) >> 16;
    c = (c + 0x7fffu + ((c >> 16) & 1u)) >> 16;
    d = (d + 0x7fffu + ((d >> 16) & 1u)) >> 16;
    return make_uint2(a | (b << 16), c | (d << 16));
}
__device__ __forceinline__ float4 unpack_bf4(uint2 p) {
    return make_float4(__uint_as_float(p.x << 16),
                       __uint_as_float(p.x & 0xffff0000u),
                       __uint_as_float(p.y << 16),
                       __uint_as_float(p.y & 0xffff0000u));
}

// ---------------------------------------------------------------------------
// Build padded sparse rows (column-ordered, deterministic). One wave per row.
__global__ void k_build_sparse(const float* __restrict__ A,
                               int* __restrict__ cnt, int* __restrict__ cols,
                               float* __restrict__ vals) {
    int n    = blockIdx.x;
    int lane = threadIdx.x;
    const float* row = A + (size_t)n * ADJLD;
    int c = 0;
    for (int c0 = 0; c0 < 384; c0 += 64) {
        int col = c0 + lane;
        float v = (col < N_) ? row[col] : 0.f;
        unsigned long long m = __ballot(v != 0.f);
        int idx = c + __popcll(m & ((1ull << lane) - 1ull));
        if (v != 0.f && idx < NNZCAP) {
            cols[n * NNZCAP + idx] = col;
            vals[n * NNZCAP + idx] = v;
        }
        c += __popcll(m);
    }
    if (c + lane < NNZCAP) {                 // zero-pad tail -> branch-free consumers
        cols[n * NNZCAP + c + lane] = 0;
        vals[n * NNZCAP + c + lane] = 0.f;
    }
    if (lane == 0) cnt[n] = (c < NNZCAP) ? c : NNZCAP;
}

// ---------------------------------------------------------------------------
// Prep: transpose + bf16-pack layer-1 W01 mats (8: stack*4+c) and reduce_w.
// WT[mat][n][k] = W0[k][n]+W1[k][n];  RT[n][k] = reduce_w[k][n].
__global__ void k_prep_w(const float* __restrict__ gadj_w,
                         const float* __restrict__ gpea_w,
                         const float* __restrict__ reduce_w,
                         ushort* __restrict__ WT, ushort* __restrict__ RT) {
    int mat = blockIdx.x;
    if (mat < 8) {
        int stack = mat >> 2, c = mat & 3;
        const float* w0 = (stack ? gpea_w : gadj_w) + (size_t)((c * L_ + 1) * 2) * 4096;
        const float* w1 = w0 + 4096;
        for (int i = 0; i < 16; ++i) {
            int e = threadIdx.x + i * 256;   // e = k*64 + n
            int k = e >> 6, n = e & 63;
            WT[((size_t)mat * 64 + n) * WPITCH + k] = bf_rne(w0[e] + w1[e]);
        }
    } else {
        for (int i = 0; i < 64; ++i) {
            int e = threadIdx.x + i * 256;   // 16384 elems; e = k*64 + n
            int k = e >> 6, n = e & 63;
            RT[(size_t)n * RPITCH + k] = bf_rne(reduce_w[e]);
        }
    }
}

// ---------------------------------------------------------------------------
// K1: fused [norm of prev cr] + gf/residual/g_init + 2-layer gate MLP.
__global__ __launch_bounds__(256, 3) void k_gate(
    const float* __restrict__ inp,
    const float* __restrict__ w_in, const float* __restrict__ b_in,
    const float* __restrict__ gconv_w, const float* __restrict__ gconv_b,
    const float* __restrict__ res_w,   const float* __restrict__ res_b,
    const float* __restrict__ cr, const float* __restrict__ partials, int it,
    const float* __restrict__ W1, const float* __restrict__ b1,
    const float* __restrict__ W2, const float* __restrict__ b2,
    float* __restrict__ residual, ushort* __restrict__ g_init,
    float* __restrict__ gate)
{
    __shared__ float Gf[64 * 68];
    __shared__ float Ws[64 * 68];
    __shared__ float Gr[64 * 68];
    int t = threadIdx.x, lane = t & 63, w = t >> 6;
    int m0 = blockIdx.x * 64;

    // ---- phase -1: LayerNorm constants from partials (it>0, 650 blocks) ----
    float mu = 0.f, rs = 0.f;
    if (it > 0) {
        float a = 0.f, b = 0.f;
        for (int i = t; i < 650; i += 256) { a += partials[i]; b += partials[650 + i]; }
        Ws[t] = a; Ws[256 + t] = b;
        __syncthreads();
        for (int off = 128; off > 0; off >>= 1) {
            if (t < off) { Ws[t] += Ws[t + off]; Ws[256 + t] += Ws[256 + t + off]; }
            __syncthreads();
        }
        const float inv = 1.f / (float)(M_ * H_);
        mu = Ws[0] * inv;
        float var = Ws[256] * inv - mu * mu;
        rs = rsqrtf(var + 1e-5f);
        __syncthreads();   // reduction reads done before W1 staging overwrites Ws
    }

    // ---- phase 0: gf / residual / g_init ----
    {
        float wa = w_in[lane], wb = w_in[H_ + lane], bi = b_in[lane];
        float gw0 = gconv_w[0], gw1 = gconv_w[1], gw2 = gconv_w[2], gw3 = gconv_w[3];
        float rw0 = res_w[0],   rw1 = res_w[1],   rw2 = res_w[2],   rw3 = res_w[3];
        float gb = gconv_b[0],  rb = res_b[0];
        int left = (it == 0) ? 0 : (3 * it + 1);
        for (int i = 0; i < 16; ++i) {
            int r = i * 4 + w;                  // wave-uniform row
            int m = m0 + r;
            int b = m / N_, n = m % N_;
            const float* ipb = inp + ((size_t)b * T_ * N_ + n) * 2;
            float v0;
            if (it > 0) v0 = (cr[(size_t)m * H_ + lane] - mu) * rs;
            else        { v0 = ipb[0] * wa + ipb[1] * wb + bi; }
            int t1 = (it == 0) ? 1 : left;
            const float* ip1 = ipb + (size_t)t1 * N_ * 2;
            const float* ip2 = ip1 + (size_t)N_ * 2;
            const float* ip3 = ip2 + (size_t)N_ * 2;
            float v1 = ip1[0] * wa + ip1[1] * wb + bi;
            float v2 = ip2[0] * wa + ip2[1] * wb + bi;
            float v3 = ip3[0] * wa + ip3[1] * wb + bi;
            Gf[r * 68 + lane] = gb + gw0 * v0 + gw1 * v1 + gw2 * v2 + gw3 * v3;
            residual[(size_t)m * H_ + lane] = rb + rw0 * v0 + rw1 * v1 + rw2 * v2 + rw3 * v3;
            g_init[(size_t)m * H_ + lane] = bf_rne(v3);
        }
    }
    // stage W1
    #pragma unroll
    for (int i = 0; i < 4; ++i) {
        int f4 = t + i * 256;
        int row = f4 >> 4, col = (f4 & 15) * 4;
        *(float4*)&Ws[row * 68 + col] = *(const float4*)&W1[row * 64 + col];
    }
    __syncthreads();

    int tx = t & 15, ty = t >> 4;
    float acc[4][4];
    #pragma unroll
    for (int i = 0; i < 4; ++i)
        #pragma unroll
        for (int j = 0; j < 4; ++j) acc[i][j] = 0.f;
    #pragma unroll 16
    for (int k = 0; k < 64; ++k) {
        float a0 = Gf[ty * 68 + k];
        float a1 = Gf[(ty + 16) * 68 + k];
        float a2 = Gf[(ty + 32) * 68 + k];
        float a3 = Gf[(ty + 48) * 68 + k];
        float4 wv = *(const float4*)&Ws[k * 68 + 4 * tx];
        float b0 = wv.x, b1v = wv.y, b2v = wv.z, b3 = wv.w;
        { float b1 = b1v, b2 = b2v; FMA16 }
    }
    float4 bi1 = *(const float4*)&b1[4 * tx];
    #pragma unroll
    for (int i = 0; i < 4; ++i) {
        float v0 = acc[i][0] + bi1.x; v0 = v0 > 0.f ? v0 : 0.f;
        float v1 = acc[i][1] + bi1.y; v1 = v1 > 0.f ? v1 : 0.f;
        float v2 = acc[i][2] + bi1.z; v2 = v2 > 0.f ? v2 : 0.f;
        float v3 = acc[i][3] + bi1.w; v3 = v3 > 0.f ? v3 : 0.f;
        *(float4*)&Gr[(ty + 16 * i) * 68 + 4 * tx] = make_float4(v0, v1, v2, v3);
    }
    for (int ch = 0; ch < 4; ++ch) {
        __syncthreads();
        #pragma unroll
        for (int i = 0; i < 4; ++i) {
            int f4 = t + i * 256;
            int row = f4 >> 4, col = (f4 & 15) * 4;
            *(float4*)&Ws[row * 68 + col] =
                *(const float4*)&W2[(size_t)row * 256 + ch * 64 + col];
        }
        __syncthreads();
        float acc2[4][4];
        #pragma unroll
        for (int i = 0; i < 4; ++i)
            #pragma unroll
            for (int j = 0; j < 4; ++j) acc2[i][j] = 0.f;
        #pragma unroll 16
        for (int k = 0; k < 64; ++k) {
            float a0 = Gr[ty * 68 + k];
            float a1 = Gr[(ty + 16) * 68 + k];
            float a2 = Gr[(ty + 32) * 68 + k];
            float a3 = Gr[(ty + 48) * 68 + k];
            float4 wv = *(const float4*)&Ws[k * 68 + 4 * tx];
            float b0 = wv.x, b1v = wv.y, b2v = wv.z, b3 = wv.w;
            { float b1 = b1v, b2 = b2v; float (*acc)[4] = acc2; FMA16 }
        }
        float4 bi2 = *(const float4*)&b2[ch * 64 + 4 * tx];
        #pragma unroll
        for (int i = 0; i < 4; ++i) {
            int m = m0 + ty + 16 * i;
            float g0 = 1.f / (1.f + expf(-(acc2[i][0] + bi2.x)));
            float g1 = 1.f / (1.f + expf(-(acc2[i][1] + bi2.y)));
            float g2 = 1.f / (1.f + expf(-(acc2[i][2] + bi2.z)));
            float g3 = 1.f / (1.f + expf(-(acc2[i][3] + bi2.w)));
            *(float4*)&gate[(size_t)m * 256 + ch * 64 + 4 * tx] = make_float4(g0, g1, g2, g3);
        }
    }
}

// ---------------------------------------------------------------------------
// K2: layer 1, both stacks; g_init bf16 (1 L2 line/row), G1 out bf16.
__global__ __launch_bounds__(256, 4) void k_layer1(
    const int*   __restrict__ cnt,    // [2N]  adj rows 0..N, pea rows N..2N
    const int*   __restrict__ cols,   // [2N][NNZCAP]
    const float* __restrict__ vals,
    const ushort* __restrict__ g_init, // [M][64] bf16
    const float* __restrict__ wadj, const float* __restrict__ badj,
    const float* __restrict__ wpea, const float* __restrict__ bpea,
    ushort* __restrict__ G1a, ushort* __restrict__ G1p)   // [M][256] bf16
{
    __shared__ float Ma[32 * 68];
    __shared__ float Mp[32 * 68];
    __shared__ float Ws[64 * 68];
    int t = threadIdx.x, lane = t & 63, w = t >> 6;
    int vb = (blockIdx.x & 7) * 82 + (blockIdx.x >> 3);   // XCD swizzle
    if (vb >= 650) return;
    int m0 = vb * 32;

    // ---- gather: lane=(rr,cl); rows w*8+rr and w*8+4+rr, both stacks ----
    {
        int cl = lane & 15, rr = lane >> 4;
        int mA = m0 + w * 8 + rr;
        int mB = mA + 4;
        int nA = mA % N_, nB = mB % N_;
        const ushort* gA = g_init + (size_t)(mA - nA) * H_ + cl * 4;
        const ushort* gB = g_init + (size_t)(mB - nB) * H_ + cl * 4;
        const int   *cA0 = cols + nA * NNZCAP,        *cB0 = cols + nB * NNZCAP;
        const float *vA0 = vals + nA * NNZCAP,        *vB0 = vals + nB * NNZCAP;
        const int   *cA1 = cols + (N_ + nA) * NNZCAP, *cB1 = cols + (N_ + nB) * NNZCAP;
        const float *vA1 = vals + (N_ + nA) * NNZCAP, *vB1 = vals + (N_ + nB) * NNZCAP;
        int jm = max(max(cnt[nA], cnt[nB]), max(cnt[N_ + nA], cnt[N_ + nB]));
        float4 aA0 = make_float4(0.f,0.f,0.f,0.f), aB0 = make_float4(0.f,0.f,0.f,0.f);
        float4 aA1 = make_float4(0.f,0.f,0.f,0.f), aB1 = make_float4(0.f,0.f,0.f,0.f);
        for (int j = 0; j < jm; j += 2) {     // zero-padded -> branch-free
            fma4(aA0, vA0[j],   unpack_bf4(*(const uint2*)&gA[cA0[j]   * H_]));
            fma4(aA0, vA0[j+1], unpack_bf4(*(const uint2*)&gA[cA0[j+1] * H_]));
            fma4(aB0, vB0[j],   unpack_bf4(*(const uint2*)&gB[cB0[j]   * H_]));
            fma4(aB0, vB0[j+1], unpack_bf4(*(const uint2*)&gB[cB0[j+1] * H_]));
            fma4(aA1, vA1[j],   unpack_bf4(*(const uint2*)&gA[cA1[j]   * H_]));
            fma4(aA1, vA1[j+1], unpack_bf4(*(const uint2*)&gA[cA1[j+1] * H_]));
            fma4(aB1, vB1[j],   unpack_bf4(*(const uint2*)&gB[cB1[j]   * H_]));
            fma4(aB1, vB1[j+1], unpack_bf4(*(const uint2*)&gB[cB1[j+1] * H_]));
        }
        *(float4*)&Ma[(w * 8 + rr) * 68 + cl * 4]     = aA0;
        *(float4*)&Ma[(w * 8 + 4 + rr) * 68 + cl * 4] = aB0;
        *(float4*)&Mp[(w * 8 + rr) * 68 + cl * 4]     = aA1;
        *(float4*)&Mp[(w * 8 + 4 + rr) * 68 + cl * 4] = aB1;
    }

    int tx = t & 15, ty = t >> 4;
    for (int sc = 0; sc < 8; ++sc) {
        int stack = sc >> 2, c = sc & 3;
        const float* wb0 = (stack ? wpea : wadj) + (size_t)c * 16384;   // layer 0
        const float* wb1 = wb0 + 4096;
        __syncthreads();   // gather done (sc=0) / prev Ws reads done (sc>0)
        #pragma unroll
        for (int i = 0; i < 4; ++i) {
            int f4 = t + i * 256;
            int row = f4 >> 4, col = (f4 & 15) * 4;
            float4 x0 = *(const float4*)&wb0[row * 64 + col];
            float4 x1 = *(const float4*)&wb1[row * 64 + col];
            *(float4*)&Ws[row * 68 + col] = make_float4(x0.x + x1.x, x0.y + x1.y,
                                                        x0.z + x1.z, x0.w + x1.w);
        }
        __syncthreads();

        const float* Msrc = stack ? Mp : Ma;
        float4 acc0 = make_float4(0.f, 0.f, 0.f, 0.f);
        float4 acc1 = make_float4(0.f, 0.f, 0.f, 0.f);
        #pragma unroll 8
        for (int k4 = 0; k4 < 64; k4 += 4) {
            float4 A0 = *(const float4*)&Msrc[ty * 68 + k4];
            float4 A1 = *(const float4*)&Msrc[(ty + 16) * 68 + k4];
            float4 W0 = *(const float4*)&Ws[(k4 + 0) * 68 + 4 * tx];
            float4 W1 = *(const float4*)&Ws[(k4 + 1) * 68 + 4 * tx];
            float4 W2 = *(const float4*)&Ws[(k4 + 2) * 68 + 4 * tx];
            float4 W3 = *(const float4*)&Ws[(k4 + 3) * 68 + 4 * tx];
            fma4(acc0, A0.x, W0); fma4(acc0, A0.y, W1); fma4(acc0, A0.z, W2); fma4(acc0, A0.w, W3);
            fma4(acc1, A1.x, W0); fma4(acc1, A1.y, W1); fma4(acc1, A1.z, W2); fma4(acc1, A1.w, W3);
        }
        const float* bias = (stack ? bpea : badj) + c * L_ * H_;   // layer 0
        float4 bi = *(const float4*)&bias[4 * tx];
        ushort* Gout = stack ? G1p : G1a;
        #pragma unroll
        for (int r = 0; r < 2; ++r) {
            float4 a = r ? acc1 : acc0;
            float v0 = a.x + bi.x; v0 = v0 > 0.f ? v0 : 0.f;
            float v1 = a.y + bi.y; v1 = v1 > 0.f ? v1 : 0.f;
            float v2 = a.z + bi.z; v2 = v2 > 0.f ? v2 : 0.f;
            float v3 = a.w + bi.w; v3 = v3 > 0.f ? v3 : 0.f;
            *(uint2*)&Gout[(size_t)(m0 + ty + 16 * r) * 256 + c * 64 + 4 * tx] =
                pack_bf4(make_float4(v0, v1, v2, v3));
        }
    }
}

// ---------------------------------------------------------------------------
// K3: layer 2 + gate mix + reduce GEMM, GEMMs via bf16 MFMA (16x16x32).
// 8 blocks/CU (latency-bound gather: maximize outstanding loads).
// Epilogue staged through LDS for fully-coalesced cr/residual traffic.
__global__ __launch_bounds__(256, 8) void k_mix(
    const int*   __restrict__ cnt,
    const int*   __restrict__ cols,
    const float* __restrict__ vals,
    const ushort* __restrict__ G1a, const ushort* __restrict__ G1p,  // [M][256] bf16
    const ushort* __restrict__ WT,   // [8][64][WPITCH] bf16 W01^T (adj c, then pea c)
    const ushort* __restrict__ RT,   // [64][RPITCH] bf16 reduce_w^T
    const float* __restrict__ badj, const float* __restrict__ bpea,
    const float* __restrict__ gate,     // [M][256]
    const float* __restrict__ reduce_b, // [64]
    const float* __restrict__ residual, // [M][64]
    float* __restrict__ cr,             // [M][64]
    float* __restrict__ partials)       // [2*650]
{
    __shared__ ushort Mt[32 * RPITCH];  // 16.9 KB (also reused as fp32 cr stage)
    __shared__ float red[512];
    int t = threadIdx.x, lane = t & 63, w = t >> 6;
    int vb = (blockIdx.x & 7) * 82 + (blockIdx.x >> 3);   // XCD swizzle
    if (vb >= 650) return;
    int m0 = vb * 32;
    int q = lane >> 4, ml = lane & 15;
    int colg = w * 16 + ml;              // this wave-lane's output column (0..63)

    // prefetch A-stack B-fragments (overlaps entire gather phase)
    bfrag BA[4][2];
    #pragma unroll
    for (int c = 0; c < 4; ++c)
        #pragma unroll
        for (int kc = 0; kc < 2; ++kc)
            BA[c][kc] = *(const bfrag*)&WT[((size_t)c * 64 + colg) * WPITCH + kc * 32 + q * 8];

    // ======== gather stack A into Mt (bf16), 2 rows x unroll 2 ========
    for (int pp = 0; pp < 8; pp += 2) {
        int ma = m0 + w * 8 + pp, mb = ma + 1;
        int na = ma % N_, nb = mb % N_;
        const ushort* ga = G1a + (size_t)(ma - na) * 256 + lane * 4;
        const ushort* gb = G1a + (size_t)(mb - nb) * 256 + lane * 4;
        const int   *cap = cols + na * NNZCAP, *cbp = cols + nb * NNZCAP;
        const float *vap = vals + na * NNZCAP, *vbp = vals + nb * NNZCAP;
        int jm = max(cnt[na], cnt[nb]);
        float4 a0 = make_float4(0.f,0.f,0.f,0.f), a1 = make_float4(0.f,0.f,0.f,0.f);
        for (int j = 0; j < jm; j += 2) {     // zero-padded -> branch-free
            fma4(a0, vap[j],   unpack_bf4(*(const uint2*)&ga[cap[j]   * 256]));
            fma4(a0, vap[j+1], unpack_bf4(*(const uint2*)&ga[cap[j+1] * 256]));
            fma4(a1, vbp[j],   unpack_bf4(*(const uint2*)&gb[cbp[j]   * 256]));
            fma4(a1, vbp[j+1], unpack_bf4(*(const uint2*)&gb[cbp[j+1] * 256]));
        }
        *(uint2*)&Mt[(w * 8 + pp) * RPITCH + lane * 4]     = pack_bf4(a0);
        *(uint2*)&Mt[(w * 8 + pp + 1) * RPITCH + lane * 4] = pack_bf4(a1);
    }
    __syncthreads();

    // ======== stack A: 4 channel GEMMs via MFMA ========
    f32x4 resv[4][2];
    f32x4 gsv[4][2];
    #pragma unroll
    for (int c = 0; c < 4; ++c) {
        float bv = badj[(c * L_ + 1) * H_ + colg];
        #pragma unroll
        for (int r = 0; r < 2; ++r) {
            bfrag A0 = *(const bfrag*)&Mt[(16 * r + ml) * RPITCH + c * 64 + q * 8];
            bfrag A1 = *(const bfrag*)&Mt[(16 * r + ml) * RPITCH + c * 64 + 32 + q * 8];
            f32x4 acc = {0.f, 0.f, 0.f, 0.f};
            acc = __builtin_amdgcn_mfma_f32_16x16x32_bf16(A0, BA[c][0], acc, 0, 0, 0);
            acc = __builtin_amdgcn_mfma_f32_16x16x32_bf16(A1, BA[c][1], acc, 0, 0, 0);
            f32x4 g4, rv;
            #pragma unroll
            for (int j = 0; j < 4; ++j) {
                int m = m0 + 16 * r + q * 4 + j;
                float g = gate[(size_t)m * 256 + c * 64 + colg];
                float v = acc[j] + bv; v = v > 0.f ? v : 0.f;
                g4[j] = g;
                rv[j] = g * v;
            }
            gsv[c][r] = g4;
            resv[c][r] = rv;
        }
    }

    // prefetch P-stack B-fragments (overlaps P gather)
    bfrag BP[4][2];
    #pragma unroll
    for (int c = 0; c < 4; ++c)
        #pragma unroll
        for (int kc = 0; kc < 2; ++kc)
            BP[c][kc] = *(const bfrag*)&WT[((size_t)(4 + c) * 64 + colg) * WPITCH + kc * 32 + q * 8];

    __syncthreads();   // all A-stage Mt reads done before overwrite

    // ======== gather stack P into Mt ========
    for (int pp = 0; pp < 8; pp += 2) {
        int ma = m0 + w * 8 + pp, mb = ma + 1;
        int na = ma % N_, nb = mb % N_;
        const ushort* ga = G1p + (size_t)(ma - na) * 256 + lane * 4;
        const ushort* gb = G1p + (size_t)(mb - nb) * 256 + lane * 4;
        const int   *cap = cols + (N_ + na) * NNZCAP, *cbp = cols + (N_ + nb) * NNZCAP;
        const float *vap = vals + (N_ + na) * NNZCAP, *vbp = vals + (N_ + nb) * NNZCAP;
        int jm = max(cnt[N_ + na], cnt[N_ + nb]);
        float4 a0 = make_float4(0.f,0.f,0.f,0.f), a1 = make_float4(0.f,0.f,0.f,0.f);
        for (int j = 0; j < jm; j += 2) {
            fma4(a0, vap[j],   unpack_bf4(*(const uint2*)&ga[cap[j]   * 256]));
            fma4(a0, vap[j+1], unpack_bf4(*(const uint2*)&ga[cap[j+1] * 256]));
            fma4(a1, vbp[j],   unpack_bf4(*(const uint2*)&gb[cbp[j]   * 256]));
            fma4(a1, vbp[j+1], unpack_bf4(*(const uint2*)&gb[cbp[j+1] * 256]));
        }
        *(uint2*)&Mt[(w * 8 + pp) * RPITCH + lane * 4]     = pack_bf4(a0);
        *(uint2*)&Mt[(w * 8 + pp + 1) * RPITCH + lane * 4] = pack_bf4(a1);
    }
    __syncthreads();

    // ======== stack P GEMMs + mix; commit mixed slice c after barrier ========
    #pragma unroll
    for (int c = 0; c < 4; ++c) {
        float bv = bpea[(c * L_ + 1) * H_ + colg];
        #pragma unroll
        for (int r = 0; r < 2; ++r) {
            bfrag A0 = *(const bfrag*)&Mt[(16 * r + ml) * RPITCH + c * 64 + q * 8];
            bfrag A1 = *(const bfrag*)&Mt[(16 * r + ml) * RPITCH + c * 64 + 32 + q * 8];
            f32x4 acc = {0.f, 0.f, 0.f, 0.f};
            acc = __builtin_amdgcn_mfma_f32_16x16x32_bf16(A0, BP[c][0], acc, 0, 0, 0);
            acc = __builtin_amdgcn_mfma_f32_16x16x32_bf16(A1, BP[c][1], acc, 0, 0, 0);
            f32x4 rv = resv[c][r];
            f32x4 g4 = gsv[c][r];
            #pragma unroll
            for (int j = 0; j < 4; ++j) {
                float v = acc[j] + bv; v = v > 0.f ? v : 0.f;
                rv[j] = rv[j] + (1.f - g4[j]) * v;
            }
            resv[c][r] = rv;
        }
        __syncthreads();   // all waves done reading slice c
        #pragma unroll
        for (int r = 0; r < 2; ++r)
            #pragma unroll
            for (int j = 0; j < 4; ++j)
                Mt[(16 * r + q * 4 + j) * RPITCH + c * 64 + colg] = bf_rne(resv[c][r][j]);
    }

    // reduce B-fragments
    bfrag RB[8];
    #pragma unroll
    for (int kc = 0; kc < 8; ++kc)
        RB[kc] = *(const bfrag*)&RT[(size_t)colg * RPITCH + kc * 32 + q * 8];
    __syncthreads();   // all commits visible

    // ======== reduce GEMM: Mt[32x256] @ reduce_w, held in regs ========
    f32x4 racc[2];
    #pragma unroll
    for (int r = 0; r < 2; ++r) {
        f32x4 acc = {0.f, 0.f, 0.f, 0.f};
        #pragma unroll
        for (int kc = 0; kc < 8; ++kc) {
            bfrag A = *(const bfrag*)&Mt[(16 * r + ml) * RPITCH + kc * 32 + q * 8];
            acc = __builtin_amdgcn_mfma_f32_16x16x32_bf16(A, RB[kc], acc, 0, 0, 0);
        }
        racc[r] = acc;
    }
    __syncthreads();   // all reduce-GEMM Mt reads done -> reuse Mt as fp32 stage

    // stage C-layout results into LDS (fp32, pitch 68)
    float* MtF = (float*)Mt;
    float bvr = reduce_b[colg];
    #pragma unroll
    for (int r = 0; r < 2; ++r)
        #pragma unroll
        for (int j = 0; j < 4; ++j)
            MtF[(16 * r + q * 4 + j) * 68 + colg] = racc[r][j] + bvr;
    __syncthreads();

    // coalesced epilogue: cr = stage + residual, with partial sums
    float s = 0.f, s2 = 0.f;
    #pragma unroll
    for (int i = 0; i < 2; ++i) {
        int idx = t * 2 + i;             // 0..511 float4s over the 32x64 tile
        int row = idx >> 4, c4 = (idx & 15) * 4;
        float4 v4 = *(const float4*)&MtF[row * 68 + c4];
        float4 rv = *(const float4*)&residual[(size_t)(m0 + row) * 64 + c4];
        v4 = make_float4(v4.x + rv.x, v4.y + rv.y, v4.z + rv.z, v4.w + rv.w);
        *(float4*)&cr[(size_t)(m0 + row) * 64 + c4] = v4;
        s += v4.x + v4.y + v4.z + v4.w;
        s2 += v4.x * v4.x + v4.y * v4.y + v4.z * v4.z + v4.w * v4.w;
    }
    red[t] = s; red[256 + t] = s2;
    __syncthreads();
    for (int off = 128; off > 0; off >>= 1) {
        if (t < off) { red[t] += red[t + off]; red[256 + t] += red[256 + t + off]; }
        __syncthreads();
    }
    if (t == 0) { partials[vb] = red[0]; partials[650 + vb] = red[256]; }
}

// ---------------------------------------------------------------------------
// K5: out = relu(ocw*norm(cr) + ocb) @ olw + olb, norm fused from partials
__global__ void k_out(const float* __restrict__ cr, const float* __restrict__ partials,
                      const float* __restrict__ ocw, const float* __restrict__ ocb,
                      const float* __restrict__ olw, const float* __restrict__ olb,
                      float* __restrict__ out) {
    __shared__ float s1[256], s2[256];
    int t = threadIdx.x;
    float a = 0.f, b2s = 0.f;
    for (int i = t; i < 650; i += 256) { a += partials[i]; b2s += partials[650 + i]; }
    s1[t] = a; s2[t] = b2s;
    __syncthreads();
    for (int off = 128; off > 0; off >>= 1) {
        if (t < off) { s1[t] += s1[t + off]; s2[t] += s2[t + off]; }
        __syncthreads();
    }
    const float inv = 1.f / (float)(M_ * H_);
    float mu  = s1[0] * inv;
    float var = s2[0] * inv - mu * mu;
    float rs  = rsqrtf(var + 1e-5f);

    int m = blockIdx.x * 256 + t;
    if (m >= M_) return;
    int b = m / N_, n = m % N_;
    float cw[P_], cb[P_], acc[P_];
    #pragma unroll
    for (int p = 0; p < P_; ++p) { cw[p] = ocw[p]; cb[p] = ocb[p]; acc[p] = 0.f; }
    const float* lr = cr + (size_t)m * H_;
    for (int h = 0; h < H_; ++h) {
        float lv = (lr[h] - mu) * rs;
        float wv = olw[h];
        #pragma unroll
        for (int p = 0; p < P_; ++p) {
            float u = cw[p] * lv + cb[p];
            u = u > 0.f ? u : 0.f;
            acc[p] += u * wv;
        }
    }
    float ob = olb[0];
    #pragma unroll
    for (int p = 0; p < P_; ++p)
        out[(size_t)(b * P_ + p) * N_ + n] = acc[p] + ob;
}

// ---------------------------------------------------------------------------
extern "C" void kernel_launch(void* const* d_in, const int* in_sizes, int n_in,
                              void* d_out, int out_size, void* d_ws, size_t ws_size,
                              hipStream_t stream) {
    const float* inp      = (const float*)d_in[0];
    const float* adj_fwd  = (const float*)d_in[1];
    const float* pea_fwd  = (const float*)d_in[3];
    const float* w_in     = (const float*)d_in[5];
    const float* b_in     = (const float*)d_in[6];
    const float* res_w    = (const float*)d_in[7];
    const float* res_b    = (const float*)d_in[8];
    const float* gconv_w  = (const float*)d_in[9];
    const float* gconv_b  = (const float*)d_in[10];
    const float* gate1_w  = (const float*)d_in[11];
    const float* gate1_b  = (const float*)d_in[12];
    const float* gate2_w  = (const float*)d_in[13];
    const float* gate2_b  = (const float*)d_in[14];
    const float* reduce_w = (const float*)d_in[15];
    const float* reduce_b = (const float*)d_in[16];
    const float* gadj_w   = (const float*)d_in[17];
    const float* gadj_b   = (const float*)d_in[18];
    const float* gpea_w   = (const float*)d_in[19];
    const float* gpea_b   = (const float*)d_in[20];
    const float* ocw      = (const float*)d_in[21];
    const float* ocb      = (const float*)d_in[22];
    const float* olw      = (const float*)d_in[23];
    const float* olb      = (const float*)d_in[24];
    float* out = (float*)d_out;

    // workspace layout — fp32 region then bf16 buffers (~58 MB total)
    float* ws       = (float*)d_ws;
    float* gate     = ws;                              // M*256
    float* residual = gate + (size_t)M_ * 256;         // M*64
    float* cr       = residual + (size_t)M_ * H_;      // M*64
    float* partials = cr + (size_t)M_ * H_;            // 1300
    int*   scnt  = (int*)(partials + 1300);            // 2*325
    int*   scols = scnt + 2 * N_;                      // 2*325*64
    float* svals = (float*)(scols + 2 * N_ * NNZCAP);  // 2*325*64
    ushort* G1a  = (ushort*)(svals + 2 * N_ * NNZCAP); // M*256 bf16
    ushort* G1p  = G1a + (size_t)M_ * 256;             // M*256 bf16
    ushort* g_init = G1p + (size_t)M_ * 256;           // M*64 bf16
    ushort* WT   = g_init + (size_t)M_ * H_;           // 8*64*WPITCH
    ushort* RT   = WT + 8 * 64 * WPITCH;               // 64*RPITCH

    k_build_sparse<<<N_, 64, 0, stream>>>(adj_fwd, scnt,      scols,              svals);
    k_build_sparse<<<N_, 64, 0, stream>>>(pea_fwd, scnt + N_, scols + N_*NNZCAP,  svals + N_*NNZCAP);
    k_prep_w<<<9, 256, 0, stream>>>(gadj_w, gpea_w, reduce_w, WT, RT);

    for (int it = 0; it < KCP; ++it) {
        k_gate<<<M_ / 64, 256, 0, stream>>>(
            inp, w_in, b_in, gconv_w, gconv_b, res_w, res_b, cr, partials, it,
            gate1_w, gate1_b, gate2_w, gate2_b, residual, g_init, gate);
        k_layer1<<<656, 256, 0, stream>>>(
            scnt, scols, svals, g_init, gadj_w, gadj_b, gpea_w, gpea_b, G1a, G1p);
        k_mix<<<656, 256, 0, stream>>>(
            scnt, scols, svals, G1a, G1p, WT, RT, gadj_b, gpea_b, gate,
            reduce_b, residual, cr, partials);
    }

    k_out<<<(M_ + 255) / 256, 256, 0, stream>>>(cr, partials, ocw, ocb, olw, olb, out);
}

// Round 15
// 775.736 us; speedup vs baseline: 1.2976x; 1.2976x over previous
//
#include <hip/hip_runtime.h>
#include <hip/hip_bf16.h>
#include <math.h>

// Problem constants
#define B_    64
#define T_    13
#define N_    325
#define H_    64
#define C_    4
#define L_    2
#define S_    4
#define P_    12
#define KCP   4            // checkpoints [4,7,10,13]
#define M_    (B_*N_)      // 20800 (= 650*32 exactly)
#define ADJLD 1300         // leading dim of combined adjacency inputs
#define NNZCAP 64          // max nonzeros per adjacency row (3% density -> mean ~10)

#define FMA16 \
  acc[0][0]+=a0*b0; acc[0][1]+=a0*b1; acc[0][2]+=a0*b2; acc[0][3]+=a0*b3; \
  acc[1][0]+=a1*b0; acc[1][1]+=a1*b1; acc[1][2]+=a1*b2; acc[1][3]+=a1*b3; \
  acc[2][0]+=a2*b0; acc[2][1]+=a2*b1; acc[2][2]+=a2*b2; acc[2][3]+=a2*b3; \
  acc[3][0]+=a3*b0; acc[3][1]+=a3*b1; acc[3][2]+=a3*b2; acc[3][3]+=a3*b3;

__device__ __forceinline__ void fma4(float4& a, float s, float4 x) {
    a.x += s * x.x; a.y += s * x.y; a.z += s * x.z; a.w += s * x.w;
}
// bf16 pack (RNE) / unpack helpers
__device__ __forceinline__ ushort bf_rne(float f) {
    unsigned u = __float_as_uint(f);
    return (ushort)((u + 0x7fffu + ((u >> 16) & 1u)) >> 16);
}
__device__ __forceinline__ uint2 pack_bf4(float4 v) {
    unsigned a = __float_as_uint(v.x), b = __float_as_uint(v.y);
    unsigned c = __float_as_uint(v.z), d = __float_as_uint(v.w);
    a = (a + 0x7fffu + ((a >> 16) & 1u)) >> 16;
    b = (b + 0x7fffu + ((b >> 16) & 1u)) >> 16;
    c = (c + 0x7fffu + ((c >> 16) & 1u)) >> 16;
    d = (d + 0x7fffu + ((d >> 16) & 1u)) >> 16;
    return make_uint2(a | (b << 16), c | (d << 16));
}
__device__ __forceinline__ float4 unpack_bf4(uint2 p) {
    return make_float4(__uint_as_float(p.x << 16),
                       __uint_as_float(p.x & 0xffff0000u),
                       __uint_as_float(p.y << 16),
                       __uint_as_float(p.y & 0xffff0000u));
}

// ---------------------------------------------------------------------------
// Build padded sparse rows (column-ordered, deterministic). One wave per row.
__global__ void k_build_sparse(const float* __restrict__ A,
                               int* __restrict__ cnt, int* __restrict__ cols,
                               float* __restrict__ vals) {
    int n    = blockIdx.x;
    int lane = threadIdx.x;
    const float* row = A + (size_t)n * ADJLD;
    int c = 0;
    for (int c0 = 0; c0 < 384; c0 += 64) {
        int col = c0 + lane;
        float v = (col < N_) ? row[col] : 0.f;
        unsigned long long m = __ballot(v != 0.f);
        int idx = c + __popcll(m & ((1ull << lane) - 1ull));
        if (v != 0.f && idx < NNZCAP) {
            cols[n * NNZCAP + idx] = col;
            vals[n * NNZCAP + idx] = v;
        }
        c += __popcll(m);
    }
    if (c + lane < NNZCAP) {                 // zero-pad tail -> branch-free consumers
        cols[n * NNZCAP + c + lane] = 0;
        vals[n * NNZCAP + c + lane] = 0.f;
    }
    if (lane == 0) cnt[n] = (c < NNZCAP) ? c : NNZCAP;
}

// ---------------------------------------------------------------------------
// K1: fused [norm of prev cr] + gf/residual/g_init + 2-layer gate MLP.
__global__ __launch_bounds__(256, 3) void k_gate(
    const float* __restrict__ inp,
    const float* __restrict__ w_in, const float* __restrict__ b_in,
    const float* __restrict__ gconv_w, const float* __restrict__ gconv_b,
    const float* __restrict__ res_w,   const float* __restrict__ res_b,
    const float* __restrict__ cr, const float* __restrict__ partials, int it,
    const float* __restrict__ W1, const float* __restrict__ b1,
    const float* __restrict__ W2, const float* __restrict__ b2,
    float* __restrict__ residual, ushort* __restrict__ g_init,
    float* __restrict__ gate)
{
    __shared__ float Gf[64 * 68];
    __shared__ float Ws[64 * 68];
    __shared__ float Gr[64 * 68];
    int t = threadIdx.x, lane = t & 63, w = t >> 6;
    int m0 = blockIdx.x * 64;

    // ---- phase -1: LayerNorm constants from partials (it>0, 650 blocks) ----
    float mu = 0.f, rs = 0.f;
    if (it > 0) {
        float a = 0.f, b = 0.f;
        for (int i = t; i < 650; i += 256) { a += partials[i]; b += partials[650 + i]; }
        Ws[t] = a; Ws[256 + t] = b;
        __syncthreads();
        for (int off = 128; off > 0; off >>= 1) {
            if (t < off) { Ws[t] += Ws[t + off]; Ws[256 + t] += Ws[256 + t + off]; }
            __syncthreads();
        }
        const float inv = 1.f / (float)(M_ * H_);
        mu = Ws[0] * inv;
        float var = Ws[256] * inv - mu * mu;
        rs = rsqrtf(var + 1e-5f);
        __syncthreads();   // reduction reads done before W1 staging overwrites Ws
    }

    // ---- phase 0: gf / residual / g_init ----
    {
        float wa = w_in[lane], wb = w_in[H_ + lane], bi = b_in[lane];
        float gw0 = gconv_w[0], gw1 = gconv_w[1], gw2 = gconv_w[2], gw3 = gconv_w[3];
        float rw0 = res_w[0],   rw1 = res_w[1],   rw2 = res_w[2],   rw3 = res_w[3];
        float gb = gconv_b[0],  rb = res_b[0];
        int left = (it == 0) ? 0 : (3 * it + 1);
        for (int i = 0; i < 16; ++i) {
            int r = i * 4 + w;                  // wave-uniform row
            int m = m0 + r;
            int b = m / N_, n = m % N_;
            const float* ipb = inp + ((size_t)b * T_ * N_ + n) * 2;
            float v0;
            if (it > 0) v0 = (cr[(size_t)m * H_ + lane] - mu) * rs;
            else        { v0 = ipb[0] * wa + ipb[1] * wb + bi; }
            int t1 = (it == 0) ? 1 : left;
            const float* ip1 = ipb + (size_t)t1 * N_ * 2;
            const float* ip2 = ip1 + (size_t)N_ * 2;
            const float* ip3 = ip2 + (size_t)N_ * 2;
            float v1 = ip1[0] * wa + ip1[1] * wb + bi;
            float v2 = ip2[0] * wa + ip2[1] * wb + bi;
            float v3 = ip3[0] * wa + ip3[1] * wb + bi;
            Gf[r * 68 + lane] = gb + gw0 * v0 + gw1 * v1 + gw2 * v2 + gw3 * v3;
            residual[(size_t)m * H_ + lane] = rb + rw0 * v0 + rw1 * v1 + rw2 * v2 + rw3 * v3;
            g_init[(size_t)m * H_ + lane] = bf_rne(v3);
        }
    }
    // stage W1
    #pragma unroll
    for (int i = 0; i < 4; ++i) {
        int f4 = t + i * 256;
        int row = f4 >> 4, col = (f4 & 15) * 4;
        *(float4*)&Ws[row * 68 + col] = *(const float4*)&W1[row * 64 + col];
    }
    __syncthreads();

    int tx = t & 15, ty = t >> 4;
    float acc[4][4];
    #pragma unroll
    for (int i = 0; i < 4; ++i)
        #pragma unroll
        for (int j = 0; j < 4; ++j) acc[i][j] = 0.f;
    #pragma unroll 16
    for (int k = 0; k < 64; ++k) {
        float a0 = Gf[ty * 68 + k];
        float a1 = Gf[(ty + 16) * 68 + k];
        float a2 = Gf[(ty + 32) * 68 + k];
        float a3 = Gf[(ty + 48) * 68 + k];
        float4 wv = *(const float4*)&Ws[k * 68 + 4 * tx];
        float b0 = wv.x, b1v = wv.y, b2v = wv.z, b3 = wv.w;
        { float b1 = b1v, b2 = b2v; FMA16 }
    }
    float4 bi1 = *(const float4*)&b1[4 * tx];
    #pragma unroll
    for (int i = 0; i < 4; ++i) {
        float v0 = acc[i][0] + bi1.x; v0 = v0 > 0.f ? v0 : 0.f;
        float v1 = acc[i][1] + bi1.y; v1 = v1 > 0.f ? v1 : 0.f;
        float v2 = acc[i][2] + bi1.z; v2 = v2 > 0.f ? v2 : 0.f;
        float v3 = acc[i][3] + bi1.w; v3 = v3 > 0.f ? v3 : 0.f;
        *(float4*)&Gr[(ty + 16 * i) * 68 + 4 * tx] = make_float4(v0, v1, v2, v3);
    }
    for (int ch = 0; ch < 4; ++ch) {
        __syncthreads();
        #pragma unroll
        for (int i = 0; i < 4; ++i) {
            int f4 = t + i * 256;
            int row = f4 >> 4, col = (f4 & 15) * 4;
            *(float4*)&Ws[row * 68 + col] =
                *(const float4*)&W2[(size_t)row * 256 + ch * 64 + col];
        }
        __syncthreads();
        float acc2[4][4];
        #pragma unroll
        for (int i = 0; i < 4; ++i)
            #pragma unroll
            for (int j = 0; j < 4; ++j) acc2[i][j] = 0.f;
        #pragma unroll 16
        for (int k = 0; k < 64; ++k) {
            float a0 = Gr[ty * 68 + k];
            float a1 = Gr[(ty + 16) * 68 + k];
            float a2 = Gr[(ty + 32) * 68 + k];
            float a3 = Gr[(ty + 48) * 68 + k];
            float4 wv = *(const float4*)&Ws[k * 68 + 4 * tx];
            float b0 = wv.x, b1v = wv.y, b2v = wv.z, b3 = wv.w;
            { float b1 = b1v, b2 = b2v; float (*acc)[4] = acc2; FMA16 }
        }
        float4 bi2 = *(const float4*)&b2[ch * 64 + 4 * tx];
        #pragma unroll
        for (int i = 0; i < 4; ++i) {
            int m = m0 + ty + 16 * i;
            float g0 = 1.f / (1.f + expf(-(acc2[i][0] + bi2.x)));
            float g1 = 1.f / (1.f + expf(-(acc2[i][1] + bi2.y)));
            float g2 = 1.f / (1.f + expf(-(acc2[i][2] + bi2.z)));
            float g3 = 1.f / (1.f + expf(-(acc2[i][3] + bi2.w)));
            *(float4*)&gate[(size_t)m * 256 + ch * 64 + 4 * tx] = make_float4(g0, g1, g2, g3);
        }
    }
}

// ---------------------------------------------------------------------------
// K2: layer 1, both stacks; g_init bf16 (1 L2 line/row), G1 out bf16.
__global__ __launch_bounds__(256, 4) void k_layer1(
    const int*   __restrict__ cnt,    // [2N]  adj rows 0..N, pea rows N..2N
    const int*   __restrict__ cols,   // [2N][NNZCAP]
    const float* __restrict__ vals,
    const ushort* __restrict__ g_init, // [M][64] bf16
    const float* __restrict__ wadj, const float* __restrict__ badj,
    const float* __restrict__ wpea, const float* __restrict__ bpea,
    ushort* __restrict__ G1a, ushort* __restrict__ G1p)   // [M][256] bf16
{
    __shared__ float Ma[32 * 68];
    __shared__ float Mp[32 * 68];
    __shared__ float Ws[64 * 68];
    int t = threadIdx.x, lane = t & 63, w = t >> 6;
    int vb = (blockIdx.x & 7) * 82 + (blockIdx.x >> 3);   // XCD swizzle
    if (vb >= 650) return;
    int m0 = vb * 32;

    // ---- gather: lane=(rr,cl); rows w*8+rr and w*8+4+rr, both stacks ----
    {
        int cl = lane & 15, rr = lane >> 4;
        int mA = m0 + w * 8 + rr;
        int mB = mA + 4;
        int nA = mA % N_, nB = mB % N_;
        const ushort* gA = g_init + (size_t)(mA - nA) * H_ + cl * 4;
        const ushort* gB = g_init + (size_t)(mB - nB) * H_ + cl * 4;
        const int   *cA0 = cols + nA * NNZCAP,        *cB0 = cols + nB * NNZCAP;
        const float *vA0 = vals + nA * NNZCAP,        *vB0 = vals + nB * NNZCAP;
        const int   *cA1 = cols + (N_ + nA) * NNZCAP, *cB1 = cols + (N_ + nB) * NNZCAP;
        const float *vA1 = vals + (N_ + nA) * NNZCAP, *vB1 = vals + (N_ + nB) * NNZCAP;
        int jm = max(max(cnt[nA], cnt[nB]), max(cnt[N_ + nA], cnt[N_ + nB]));
        float4 aA0 = make_float4(0.f,0.f,0.f,0.f), aB0 = make_float4(0.f,0.f,0.f,0.f);
        float4 aA1 = make_float4(0.f,0.f,0.f,0.f), aB1 = make_float4(0.f,0.f,0.f,0.f);
        for (int j = 0; j < jm; j += 2) {     // zero-padded -> branch-free
            fma4(aA0, vA0[j],   unpack_bf4(*(const uint2*)&gA[cA0[j]   * H_]));
            fma4(aA0, vA0[j+1], unpack_bf4(*(const uint2*)&gA[cA0[j+1] * H_]));
            fma4(aB0, vB0[j],   unpack_bf4(*(const uint2*)&gB[cB0[j]   * H_]));
            fma4(aB0, vB0[j+1], unpack_bf4(*(const uint2*)&gB[cB0[j+1] * H_]));
            fma4(aA1, vA1[j],   unpack_bf4(*(const uint2*)&gA[cA1[j]   * H_]));
            fma4(aA1, vA1[j+1], unpack_bf4(*(const uint2*)&gA[cA1[j+1] * H_]));
            fma4(aB1, vB1[j],   unpack_bf4(*(const uint2*)&gB[cB1[j]   * H_]));
            fma4(aB1, vB1[j+1], unpack_bf4(*(const uint2*)&gB[cB1[j+1] * H_]));
        }
        *(float4*)&Ma[(w * 8 + rr) * 68 + cl * 4]     = aA0;
        *(float4*)&Ma[(w * 8 + 4 + rr) * 68 + cl * 4] = aB0;
        *(float4*)&Mp[(w * 8 + rr) * 68 + cl * 4]     = aA1;
        *(float4*)&Mp[(w * 8 + 4 + rr) * 68 + cl * 4] = aB1;
    }

    int tx = t & 15, ty = t >> 4;
    for (int sc = 0; sc < 8; ++sc) {
        int stack = sc >> 2, c = sc & 3;
        const float* wb0 = (stack ? wpea : wadj) + (size_t)c * 16384;   // layer 0
        const float* wb1 = wb0 + 4096;
        __syncthreads();   // gather done (sc=0) / prev Ws reads done (sc>0)
        #pragma unroll
        for (int i = 0; i < 4; ++i) {
            int f4 = t + i * 256;
            int row = f4 >> 4, col = (f4 & 15) * 4;
            float4 x0 = *(const float4*)&wb0[row * 64 + col];
            float4 x1 = *(const float4*)&wb1[row * 64 + col];
            *(float4*)&Ws[row * 68 + col] = make_float4(x0.x + x1.x, x0.y + x1.y,
                                                        x0.z + x1.z, x0.w + x1.w);
        }
        __syncthreads();

        const float* Msrc = stack ? Mp : Ma;
        float4 acc0 = make_float4(0.f, 0.f, 0.f, 0.f);
        float4 acc1 = make_float4(0.f, 0.f, 0.f, 0.f);
        #pragma unroll 8
        for (int k4 = 0; k4 < 64; k4 += 4) {
            float4 A0 = *(const float4*)&Msrc[ty * 68 + k4];
            float4 A1 = *(const float4*)&Msrc[(ty + 16) * 68 + k4];
            float4 W0 = *(const float4*)&Ws[(k4 + 0) * 68 + 4 * tx];
            float4 W1 = *(const float4*)&Ws[(k4 + 1) * 68 + 4 * tx];
            float4 W2 = *(const float4*)&Ws[(k4 + 2) * 68 + 4 * tx];
            float4 W3 = *(const float4*)&Ws[(k4 + 3) * 68 + 4 * tx];
            fma4(acc0, A0.x, W0); fma4(acc0, A0.y, W1); fma4(acc0, A0.z, W2); fma4(acc0, A0.w, W3);
            fma4(acc1, A1.x, W0); fma4(acc1, A1.y, W1); fma4(acc1, A1.z, W2); fma4(acc1, A1.w, W3);
        }
        const float* bias = (stack ? bpea : badj) + c * L_ * H_;   // layer 0
        float4 bi = *(const float4*)&bias[4 * tx];
        ushort* Gout = stack ? G1p : G1a;
        #pragma unroll
        for (int r = 0; r < 2; ++r) {
            float4 a = r ? acc1 : acc0;
            float v0 = a.x + bi.x; v0 = v0 > 0.f ? v0 : 0.f;
            float v1 = a.y + bi.y; v1 = v1 > 0.f ? v1 : 0.f;
            float v2 = a.z + bi.z; v2 = v2 > 0.f ? v2 : 0.f;
            float v3 = a.w + bi.w; v3 = v3 > 0.f ? v3 : 0.f;
            *(uint2*)&Gout[(size_t)(m0 + ty + 16 * r) * 256 + c * 64 + 4 * tx] =
                pack_bf4(make_float4(v0, v1, v2, v3));
        }
    }
}

// ---------------------------------------------------------------------------
// K3: layer 2 + gate mix + reduce GEMM + partial sums, all fused (R11-proven).
// Separate A/P gather phases, 2 rows x unroll 2, fp32 Mt; mix committed
// in-place into Mt's per-channel slice; then cr = Mt @ reduce_w + residual.
__global__ __launch_bounds__(256, 3) void k_mix(
    const int*   __restrict__ cnt,
    const int*   __restrict__ cols,
    const float* __restrict__ vals,
    const ushort* __restrict__ G1a, const ushort* __restrict__ G1p,  // [M][256] bf16
    const float* __restrict__ wadj, const float* __restrict__ badj,
    const float* __restrict__ wpea, const float* __restrict__ bpea,
    const float* __restrict__ gate,     // [M][256]
    const float* __restrict__ reduce_w, // [256][64]
    const float* __restrict__ reduce_b, // [64]
    const float* __restrict__ residual, // [M][64]
    float* __restrict__ cr,             // [M][64]
    float* __restrict__ partials)       // [2*650]
{
    __shared__ float Mt[32 * 260];
    __shared__ float Ws[64 * 68];
    int t = threadIdx.x, lane = t & 63, w = t >> 6;
    int vb = (blockIdx.x & 7) * 82 + (blockIdx.x >> 3);   // XCD swizzle
    if (vb >= 650) return;
    int m0 = vb * 32;
    int tx = t & 15, ty = t >> 4;

    float4 res[4][2];   // gate*relu(adj) -> then full mix, carried in regs
    float4 gsv[4][2];   // saved gate

    // ======== stack A gather: 2 rows x unroll 2, bf16 unpack ========
    for (int pp = 0; pp < 8; pp += 2) {
        int ma = m0 + w * 8 + pp, mb = ma + 1;
        int na = ma % N_, nb = mb % N_;
        const ushort* ga = G1a + (size_t)(ma - na) * 256 + lane * 4;
        const ushort* gb = G1a + (size_t)(mb - nb) * 256 + lane * 4;
        const int   *cap = cols + na * NNZCAP, *cbp = cols + nb * NNZCAP;
        const float *vap = vals + na * NNZCAP, *vbp = vals + nb * NNZCAP;
        int jm = max(cnt[na], cnt[nb]);
        float4 a0 = make_float4(0.f,0.f,0.f,0.f), a1 = make_float4(0.f,0.f,0.f,0.f);
        for (int j = 0; j < jm; j += 2) {     // zero-padded -> branch-free
            float w00 = vap[j], w01 = vap[j+1];
            float w10 = vbp[j], w11 = vbp[j+1];
            float4 x00 = unpack_bf4(*(const uint2*)&ga[cap[j]   * 256]);
            float4 x01 = unpack_bf4(*(const uint2*)&ga[cap[j+1] * 256]);
            float4 x10 = unpack_bf4(*(const uint2*)&gb[cbp[j]   * 256]);
            float4 x11 = unpack_bf4(*(const uint2*)&gb[cbp[j+1] * 256]);
            fma4(a0, w00, x00); fma4(a0, w01, x01);
            fma4(a1, w10, x10); fma4(a1, w11, x11);
        }
        *(float4*)&Mt[(w * 8 + pp) * 260 + lane * 4]     = a0;
        *(float4*)&Mt[(w * 8 + pp + 1) * 260 + lane * 4] = a1;
    }

    #pragma unroll
    for (int c = 0; c < 4; ++c) {
        __syncthreads();
        const float* w0 = wadj + (size_t)c * 16384 + 8192;   // layer 1
        const float* w1 = w0 + 4096;
        #pragma unroll
        for (int i = 0; i < 4; ++i) {
            int f4 = t + i * 256;
            int row = f4 >> 4, col = (f4 & 15) * 4;
            float4 x0 = *(const float4*)&w0[row * 64 + col];
            float4 x1 = *(const float4*)&w1[row * 64 + col];
            *(float4*)&Ws[row * 68 + col] = make_float4(x0.x + x1.x, x0.y + x1.y,
                                                        x0.z + x1.z, x0.w + x1.w);
        }
        __syncthreads();
        float4 acc0 = make_float4(0.f,0.f,0.f,0.f), acc1 = make_float4(0.f,0.f,0.f,0.f);
        #pragma unroll 8
        for (int k4 = 0; k4 < 64; k4 += 4) {
            float4 A0 = *(const float4*)&Mt[ty * 260 + c * 64 + k4];
            float4 A1 = *(const float4*)&Mt[(ty + 16) * 260 + c * 64 + k4];
            float4 W0 = *(const float4*)&Ws[(k4 + 0) * 68 + 4 * tx];
            float4 W1 = *(const float4*)&Ws[(k4 + 1) * 68 + 4 * tx];
            float4 W2 = *(const float4*)&Ws[(k4 + 2) * 68 + 4 * tx];
            float4 W3 = *(const float4*)&Ws[(k4 + 3) * 68 + 4 * tx];
            fma4(acc0, A0.x, W0); fma4(acc0, A0.y, W1); fma4(acc0, A0.z, W2); fma4(acc0, A0.w, W3);
            fma4(acc1, A1.x, W0); fma4(acc1, A1.y, W1); fma4(acc1, A1.z, W2); fma4(acc1, A1.w, W3);
        }
        float4 bA = *(const float4*)&badj[(c * L_ + 1) * H_ + 4 * tx];
        #pragma unroll
        for (int r = 0; r < 2; ++r) {
            float4 a = r ? acc1 : acc0;
            float v0 = a.x + bA.x; v0 = v0 > 0.f ? v0 : 0.f;
            float v1 = a.y + bA.y; v1 = v1 > 0.f ? v1 : 0.f;
            float v2 = a.z + bA.z; v2 = v2 > 0.f ? v2 : 0.f;
            float v3 = a.w + bA.w; v3 = v3 > 0.f ? v3 : 0.f;
            size_t o = (size_t)(m0 + ty + 16 * r) * 256 + c * 64 + 4 * tx;
            float4 g = *(const float4*)&gate[o];
            gsv[c][r] = g;
            res[c][r] = make_float4(g.x * v0, g.y * v1, g.z * v2, g.w * v3);
        }
    }

    // ======== stack P: re-gather, mix into registers, commit to Mt ========
    __syncthreads();   // all Mt reads done before overwrite
    for (int pp = 0; pp < 8; pp += 2) {
        int ma = m0 + w * 8 + pp, mb = ma + 1;
        int na = ma % N_, nb = mb % N_;
        const ushort* ga = G1p + (size_t)(ma - na) * 256 + lane * 4;
        const ushort* gb = G1p + (size_t)(mb - nb) * 256 + lane * 4;
        const int   *cap = cols + (N_ + na) * NNZCAP, *cbp = cols + (N_ + nb) * NNZCAP;
        const float *vap = vals + (N_ + na) * NNZCAP, *vbp = vals + (N_ + nb) * NNZCAP;
        int jm = max(cnt[N_ + na], cnt[N_ + nb]);
        float4 a0 = make_float4(0.f,0.f,0.f,0.f), a1 = make_float4(0.f,0.f,0.f,0.f);
        for (int j = 0; j < jm; j += 2) {
            float w00 = vap[j], w01 = vap[j+1];
            float w10 = vbp[j], w11 = vbp[j+1];
            float4 x00 = unpack_bf4(*(const uint2*)&ga[cap[j]   * 256]);
            float4 x01 = unpack_bf4(*(const uint2*)&ga[cap[j+1] * 256]);
            float4 x10 = unpack_bf4(*(const uint2*)&gb[cbp[j]   * 256]);
            float4 x11 = unpack_bf4(*(const uint2*)&gb[cbp[j+1] * 256]);
            fma4(a0, w00, x00); fma4(a0, w01, x01);
            fma4(a1, w10, x10); fma4(a1, w11, x11);
        }
        *(float4*)&Mt[(w * 8 + pp) * 260 + lane * 4]     = a0;
        *(float4*)&Mt[(w * 8 + pp + 1) * 260 + lane * 4] = a1;
    }

    #pragma unroll
    for (int c = 0; c < 4; ++c) {
        __syncthreads();   // prev GEMM's slice reads done -> safe to commit c-1
        if (c > 0) {
            *(float4*)&Mt[ty * 260 + (c - 1) * 64 + 4 * tx]        = res[c - 1][0];
            *(float4*)&Mt[(ty + 16) * 260 + (c - 1) * 64 + 4 * tx] = res[c - 1][1];
        }
        const float* w0 = wpea + (size_t)c * 16384 + 8192;   // layer 1
        const float* w1 = w0 + 4096;
        #pragma unroll
        for (int i = 0; i < 4; ++i) {
            int f4 = t + i * 256;
            int row = f4 >> 4, col = (f4 & 15) * 4;
            float4 x0 = *(const float4*)&w0[row * 64 + col];
            float4 x1 = *(const float4*)&w1[row * 64 + col];
            *(float4*)&Ws[row * 68 + col] = make_float4(x0.x + x1.x, x0.y + x1.y,
                                                        x0.z + x1.z, x0.w + x1.w);
        }
        __syncthreads();
        float4 acc0 = make_float4(0.f,0.f,0.f,0.f), acc1 = make_float4(0.f,0.f,0.f,0.f);
        #pragma unroll 8
        for (int k4 = 0; k4 < 64; k4 += 4) {
            float4 A0 = *(const float4*)&Mt[ty * 260 + c * 64 + k4];
            float4 A1 = *(const float4*)&Mt[(ty + 16) * 260 + c * 64 + k4];
            float4 W0 = *(const float4*)&Ws[(k4 + 0) * 68 + 4 * tx];
            float4 W1 = *(const float4*)&Ws[(k4 + 1) * 68 + 4 * tx];
            float4 W2 = *(const float4*)&Ws[(k4 + 2) * 68 + 4 * tx];
            float4 W3 = *(const float4*)&Ws[(k4 + 3) * 68 + 4 * tx];
            fma4(acc0, A0.x, W0); fma4(acc0, A0.y, W1); fma4(acc0, A0.z, W2); fma4(acc0, A0.w, W3);
            fma4(acc1, A1.x, W0); fma4(acc1, A1.y, W1); fma4(acc1, A1.z, W2); fma4(acc1, A1.w, W3);
        }
        float4 bP = *(const float4*)&bpea[(c * L_ + 1) * H_ + 4 * tx];
        #pragma unroll
        for (int r = 0; r < 2; ++r) {
            float4 p = r ? acc1 : acc0;
            float v0 = p.x + bP.x; v0 = v0 > 0.f ? v0 : 0.f;
            float v1 = p.y + bP.y; v1 = v1 > 0.f ? v1 : 0.f;
            float v2 = p.z + bP.z; v2 = v2 > 0.f ? v2 : 0.f;
            float v3 = p.w + bP.w; v3 = v3 > 0.f ? v3 : 0.f;
            float4 g  = gsv[c][r];
            float4 rr = res[c][r];
            res[c][r] = make_float4(rr.x + (1.f - g.x) * v0,
                                    rr.y + (1.f - g.y) * v1,
                                    rr.z + (1.f - g.z) * v2,
                                    rr.w + (1.f - g.w) * v3);
        }
    }
    __syncthreads();   // last GEMM's slice-3 reads done
    *(float4*)&Mt[ty * 260 + 3 * 64 + 4 * tx]        = res[3][0];
    *(float4*)&Mt[(ty + 16) * 260 + 3 * 64 + 4 * tx] = res[3][1];

    // ======== reduce GEMM: cr = Mt[32x256] @ reduce_w + bias + residual ======
    float4 racc0 = make_float4(0.f,0.f,0.f,0.f), racc1 = make_float4(0.f,0.f,0.f,0.f);
    for (int kk = 0; kk < 4; ++kk) {
        __syncthreads();   // Mt commits visible (kk=0) / prev Ws reads done
        #pragma unroll
        for (int i = 0; i < 4; ++i) {
            int f4 = t + i * 256;
            int row = f4 >> 4, col = (f4 & 15) * 4;
            *(float4*)&Ws[row * 68 + col] =
                *(const float4*)&reduce_w[(size_t)(kk * 64 + row) * 64 + col];
        }
        __syncthreads();
        #pragma unroll 8
        for (int k4 = 0; k4 < 64; k4 += 4) {
            float4 A0 = *(const float4*)&Mt[ty * 260 + kk * 64 + k4];
            float4 A1 = *(const float4*)&Mt[(ty + 16) * 260 + kk * 64 + k4];
            float4 W0 = *(const float4*)&Ws[(k4 + 0) * 68 + 4 * tx];
            float4 W1 = *(const float4*)&Ws[(k4 + 1) * 68 + 4 * tx];
            float4 W2 = *(const float4*)&Ws[(k4 + 2) * 68 + 4 * tx];
            float4 W3 = *(const float4*)&Ws[(k4 + 3) * 68 + 4 * tx];
            fma4(racc0, A0.x, W0); fma4(racc0, A0.y, W1); fma4(racc0, A0.z, W2); fma4(racc0, A0.w, W3);
            fma4(racc1, A1.x, W0); fma4(racc1, A1.y, W1); fma4(racc1, A1.z, W2); fma4(racc1, A1.w, W3);
        }
    }
    float4 bi = *(const float4*)&reduce_b[4 * tx];
    float s = 0.f, s2 = 0.f;
    #pragma unroll
    for (int r = 0; r < 2; ++r) {
        int m = m0 + ty + 16 * r;
        float4 a = r ? racc1 : racc0;
        float4 rv = *(const float4*)&residual[(size_t)m * 64 + 4 * tx];
        float v0 = a.x + bi.x + rv.x;
        float v1 = a.y + bi.y + rv.y;
        float v2 = a.z + bi.z + rv.z;
        float v3 = a.w + bi.w + rv.w;
        *(float4*)&cr[(size_t)m * 64 + 4 * tx] = make_float4(v0, v1, v2, v3);
        s += v0 + v1 + v2 + v3;
        s2 += v0 * v0 + v1 * v1 + v2 * v2 + v3 * v3;
    }
    __syncthreads();   // Ws reads done; reuse as reduction scratch
    float* r1 = Ws;
    float* r2 = Ws + 256;
    r1[t] = s; r2[t] = s2;
    __syncthreads();
    for (int off = 128; off > 0; off >>= 1) {
        if (t < off) { r1[t] += r1[t + off]; r2[t] += r2[t + off]; }
        __syncthreads();
    }
    if (t == 0) { partials[vb] = r1[0]; partials[650 + vb] = r2[0]; }
}

// ---------------------------------------------------------------------------
// K5: out = relu(ocw*norm(cr) + ocb) @ olw + olb, norm fused from partials
__global__ void k_out(const float* __restrict__ cr, const float* __restrict__ partials,
                      const float* __restrict__ ocw, const float* __restrict__ ocb,
                      const float* __restrict__ olw, const float* __restrict__ olb,
                      float* __restrict__ out) {
    __shared__ float s1[256], s2[256];
    int t = threadIdx.x;
    float a = 0.f, b2s = 0.f;
    for (int i = t; i < 650; i += 256) { a += partials[i]; b2s += partials[650 + i]; }
    s1[t] = a; s2[t] = b2s;
    __syncthreads();
    for (int off = 128; off > 0; off >>= 1) {
        if (t < off) { s1[t] += s1[t + off]; s2[t] += s2[t + off]; }
        __syncthreads();
    }
    const float inv = 1.f / (float)(M_ * H_);
    float mu  = s1[0] * inv;
    float var = s2[0] * inv - mu * mu;
    float rs  = rsqrtf(var + 1e-5f);

    int m = blockIdx.x * 256 + t;
    if (m >= M_) return;
    int b = m / N_, n = m % N_;
    float cw[P_], cb[P_], acc[P_];
    #pragma unroll
    for (int p = 0; p < P_; ++p) { cw[p] = ocw[p]; cb[p] = ocb[p]; acc[p] = 0.f; }
    const float* lr = cr + (size_t)m * H_;
    for (int h = 0; h < H_; ++h) {
        float lv = (lr[h] - mu) * rs;
        float wv = olw[h];
        #pragma unroll
        for (int p = 0; p < P_; ++p) {
            float u = cw[p] * lv + cb[p];
            u = u > 0.f ? u : 0.f;
            acc[p] += u * wv;
        }
    }
    float ob = olb[0];
    #pragma unroll
    for (int p = 0; p < P_; ++p)
        out[(size_t)(b * P_ + p) * N_ + n] = acc[p] + ob;
}

// ---------------------------------------------------------------------------
extern "C" void kernel_launch(void* const* d_in, const int* in_sizes, int n_in,
                              void* d_out, int out_size, void* d_ws, size_t ws_size,
                              hipStream_t stream) {
    const float* inp      = (const float*)d_in[0];
    const float* adj_fwd  = (const float*)d_in[1];
    const float* pea_fwd  = (const float*)d_in[3];
    const float* w_in     = (const float*)d_in[5];
    const float* b_in     = (const float*)d_in[6];
    const float* res_w    = (const float*)d_in[7];
    const float* res_b    = (const float*)d_in[8];
    const float* gconv_w  = (const float*)d_in[9];
    const float* gconv_b  = (const float*)d_in[10];
    const float* gate1_w  = (const float*)d_in[11];
    const float* gate1_b  = (const float*)d_in[12];
    const float* gate2_w  = (const float*)d_in[13];
    const float* gate2_b  = (const float*)d_in[14];
    const float* reduce_w = (const float*)d_in[15];
    const float* reduce_b = (const float*)d_in[16];
    const float* gadj_w   = (const float*)d_in[17];
    const float* gadj_b   = (const float*)d_in[18];
    const float* gpea_w   = (const float*)d_in[19];
    const float* gpea_b   = (const float*)d_in[20];
    const float* ocw      = (const float*)d_in[21];
    const float* ocb      = (const float*)d_in[22];
    const float* olw      = (const float*)d_in[23];
    const float* olb      = (const float*)d_in[24];
    float* out = (float*)d_out;

    // workspace layout — fp32 region then bf16 buffers (~58 MB total)
    float* ws       = (float*)d_ws;
    float* gate     = ws;                              // M*256
    float* residual = gate + (size_t)M_ * 256;         // M*64
    float* cr       = residual + (size_t)M_ * H_;      // M*64
    float* partials = cr + (size_t)M_ * H_;            // 1300
    int*   scnt  = (int*)(partials + 1300);            // 2*325
    int*   scols = scnt + 2 * N_;                      // 2*325*64
    float* svals = (float*)(scols + 2 * N_ * NNZCAP);  // 2*325*64
    ushort* G1a  = (ushort*)(svals + 2 * N_ * NNZCAP); // M*256 bf16
    ushort* G1p  = G1a + (size_t)M_ * 256;             // M*256 bf16
    ushort* g_init = G1p + (size_t)M_ * 256;           // M*64 bf16

    k_build_sparse<<<N_, 64, 0, stream>>>(adj_fwd, scnt,      scols,              svals);
    k_build_sparse<<<N_, 64, 0, stream>>>(pea_fwd, scnt + N_, scols + N_*NNZCAP,  svals + N_*NNZCAP);

    for (int it = 0; it < KCP; ++it) {
        k_gate<<<M_ / 64, 256, 0, stream>>>(
            inp, w_in, b_in, gconv_w, gconv_b, res_w, res_b, cr, partials, it,
            gate1_w, gate1_b, gate2_w, gate2_b, residual, g_init, gate);
        k_layer1<<<656, 256, 0, stream>>>(
            scnt, scols, svals, g_init, gadj_w, gadj_b, gpea_w, gpea_b, G1a, G1p);
        k_mix<<<656, 256, 0, stream>>>(
            scnt, scols, svals, G1a, G1p, gadj_w, gadj_b, gpea_w, gpea_b, gate,
            reduce_w, reduce_b, residual, cr, partials);
    }

    k_out<<<(M_ + 255) / 256, 256, 0, stream>>>(cr, partials, ocw, ocb, olw, olb, out);
}

// Round 16
// 709.370 us; speedup vs baseline: 1.4190x; 1.0936x over previous
//
#include <hip/hip_runtime.h>
#include <hip/hip_bf16.h>
#include <math.h>

// Problem constants
#define B_    64
#define T_    13
#define N_    325
#define H_    64
#define C_    4
#define L_    2
#define S_    4
#define P_    12
#define KCP   4            // checkpoints [4,7,10,13]
#define M_    (B_*N_)      // 20800 (= 650*32 exactly)
#define ADJLD 1300         // leading dim of combined adjacency inputs
#define NNZCAP 64          // max nonzeros per adjacency row (3% density -> mean ~10)

__device__ __forceinline__ void fma4(float4& a, float s, float4 x) {
    a.x += s * x.x; a.y += s * x.y; a.z += s * x.z; a.w += s * x.w;
}
// bf16 pack (RNE) / unpack helpers
__device__ __forceinline__ ushort bf_rne(float f) {
    unsigned u = __float_as_uint(f);
    return (ushort)((u + 0x7fffu + ((u >> 16) & 1u)) >> 16);
}
__device__ __forceinline__ uint2 pack_bf4(float4 v) {
    unsigned a = __float_as_uint(v.x), b = __float_as_uint(v.y);
    unsigned c = __float_as_uint(v.z), d = __float_as_uint(v.w);
    a = (a + 0x7fffu + ((a >> 16) & 1u)) >> 16;
    b = (b + 0x7fffu + ((b >> 16) & 1u)) >> 16;
    c = (c + 0x7fffu + ((c >> 16) & 1u)) >> 16;
    d = (d + 0x7fffu + ((d >> 16) & 1u)) >> 16;
    return make_uint2(a | (b << 16), c | (d << 16));
}
__device__ __forceinline__ float4 unpack_bf4(uint2 p) {
    return make_float4(__uint_as_float(p.x << 16),
                       __uint_as_float(p.x & 0xffff0000u),
                       __uint_as_float(p.y << 16),
                       __uint_as_float(p.y & 0xffff0000u));
}

// ---------------------------------------------------------------------------
// Build padded sparse rows (column-ordered, deterministic). One wave per row.
__global__ void k_build_sparse(const float* __restrict__ A,
                               int* __restrict__ cnt, int* __restrict__ cols,
                               float* __restrict__ vals) {
    int n    = blockIdx.x;
    int lane = threadIdx.x;
    const float* row = A + (size_t)n * ADJLD;
    int c = 0;
    for (int c0 = 0; c0 < 384; c0 += 64) {
        int col = c0 + lane;
        float v = (col < N_) ? row[col] : 0.f;
        unsigned long long m = __ballot(v != 0.f);
        int idx = c + __popcll(m & ((1ull << lane) - 1ull));
        if (v != 0.f && idx < NNZCAP) {
            cols[n * NNZCAP + idx] = col;
            vals[n * NNZCAP + idx] = v;
        }
        c += __popcll(m);
    }
    if (c + lane < NNZCAP) {                 // zero-pad tail -> branch-free consumers
        cols[n * NNZCAP + c + lane] = 0;
        vals[n * NNZCAP + c + lane] = 0.f;
    }
    if (lane == 0) cnt[n] = (c < NNZCAP) ? c : NNZCAP;
}

// ---------------------------------------------------------------------------
// K0: g_init for ALL checkpoints (last-independent): x[:, 3it+3] @ w_in + b_in
__global__ void k_ginit(const float* __restrict__ inp,
                        const float* __restrict__ w_in, const float* __restrict__ b_in,
                        ushort* __restrict__ g_init4) {     // [4][M][64] bf16
    int idx = blockIdx.x * 256 + threadIdx.x;   // over 4*M*H = 5,324,800
    if (idx >= 4 * M_ * H_) return;
    int h  = idx & 63;
    int r  = idx >> 6;           // it*M + m
    int it = r / M_;
    int m  = r - it * M_;
    int b  = m / N_, n = m % N_;
    int tt = 3 * it + 3;
    const float* ip = inp + ((size_t)(b * T_ + tt) * N_ + n) * 2;
    g_init4[idx] = bf_rne(ip[0] * w_in[h] + ip[1] * w_in[H_ + h] + b_in[h]);
}

// ---------------------------------------------------------------------------
// K1: fused [norm of prev cr] + gf/residual + 2-layer gate MLP. 32-row tiles
// (grid 650) for occupancy; g_init moved to k_ginit.
__global__ __launch_bounds__(256, 3) void k_gate(
    const float* __restrict__ inp,
    const float* __restrict__ w_in, const float* __restrict__ b_in,
    const float* __restrict__ gconv_w, const float* __restrict__ gconv_b,
    const float* __restrict__ res_w,   const float* __restrict__ res_b,
    const float* __restrict__ cr, const float* __restrict__ partials, int it,
    const float* __restrict__ W1, const float* __restrict__ b1,
    const float* __restrict__ W2, const float* __restrict__ b2,
    float* __restrict__ residual,
    float* __restrict__ gate)
{
    __shared__ float Gf[32 * 68];
    __shared__ float Ws[64 * 68];
    __shared__ float Gr[32 * 68];
    int t = threadIdx.x, lane = t & 63, w = t >> 6;
    int m0 = blockIdx.x * 32;

    // ---- phase -1: LayerNorm constants from partials (it>0, 650 blocks) ----
    float mu = 0.f, rs = 0.f;
    if (it > 0) {
        float a = 0.f, b = 0.f;
        for (int i = t; i < 650; i += 256) { a += partials[i]; b += partials[650 + i]; }
        Ws[t] = a; Ws[256 + t] = b;
        __syncthreads();
        for (int off = 128; off > 0; off >>= 1) {
            if (t < off) { Ws[t] += Ws[t + off]; Ws[256 + t] += Ws[256 + t + off]; }
            __syncthreads();
        }
        const float inv = 1.f / (float)(M_ * H_);
        mu = Ws[0] * inv;
        float var = Ws[256] * inv - mu * mu;
        rs = rsqrtf(var + 1e-5f);
        __syncthreads();   // reduction reads done before W1 staging overwrites Ws
    }

    // ---- phase 0: gf / residual (32 rows, 8 per wave) ----
    {
        float wa = w_in[lane], wb = w_in[H_ + lane], bi = b_in[lane];
        float gw0 = gconv_w[0], gw1 = gconv_w[1], gw2 = gconv_w[2], gw3 = gconv_w[3];
        float rw0 = res_w[0],   rw1 = res_w[1],   rw2 = res_w[2],   rw3 = res_w[3];
        float gb = gconv_b[0],  rb = res_b[0];
        int left = (it == 0) ? 0 : (3 * it + 1);
        for (int i = 0; i < 8; ++i) {
            int r = i * 4 + w;                  // wave-uniform row
            int m = m0 + r;
            int b = m / N_, n = m % N_;
            const float* ipb = inp + ((size_t)b * T_ * N_ + n) * 2;
            float v0;
            if (it > 0) v0 = (cr[(size_t)m * H_ + lane] - mu) * rs;
            else        { v0 = ipb[0] * wa + ipb[1] * wb + bi; }
            int t1 = (it == 0) ? 1 : left;
            const float* ip1 = ipb + (size_t)t1 * N_ * 2;
            const float* ip2 = ip1 + (size_t)N_ * 2;
            const float* ip3 = ip2 + (size_t)N_ * 2;
            float v1 = ip1[0] * wa + ip1[1] * wb + bi;
            float v2 = ip2[0] * wa + ip2[1] * wb + bi;
            float v3 = ip3[0] * wa + ip3[1] * wb + bi;
            Gf[r * 68 + lane] = gb + gw0 * v0 + gw1 * v1 + gw2 * v2 + gw3 * v3;
            residual[(size_t)m * H_ + lane] = rb + rw0 * v0 + rw1 * v1 + rw2 * v2 + rw3 * v3;
        }
    }
    // stage W1 [64x64]
    #pragma unroll
    for (int i = 0; i < 4; ++i) {
        int f4 = t + i * 256;
        int row = f4 >> 4, col = (f4 & 15) * 4;
        *(float4*)&Ws[row * 68 + col] = *(const float4*)&W1[row * 64 + col];
    }
    __syncthreads();

    int tx = t & 15, ty = t >> 4;
    // GEMM1: Gr = relu(Gf[32x64] @ W1 + b1)
    {
        float4 acc0 = make_float4(0.f,0.f,0.f,0.f), acc1 = make_float4(0.f,0.f,0.f,0.f);
        #pragma unroll 8
        for (int k4 = 0; k4 < 64; k4 += 4) {
            float4 A0 = *(const float4*)&Gf[ty * 68 + k4];
            float4 A1 = *(const float4*)&Gf[(ty + 16) * 68 + k4];
            float4 W0 = *(const float4*)&Ws[(k4 + 0) * 68 + 4 * tx];
            float4 W1v = *(const float4*)&Ws[(k4 + 1) * 68 + 4 * tx];
            float4 W2v = *(const float4*)&Ws[(k4 + 2) * 68 + 4 * tx];
            float4 W3v = *(const float4*)&Ws[(k4 + 3) * 68 + 4 * tx];
            fma4(acc0, A0.x, W0); fma4(acc0, A0.y, W1v); fma4(acc0, A0.z, W2v); fma4(acc0, A0.w, W3v);
            fma4(acc1, A1.x, W0); fma4(acc1, A1.y, W1v); fma4(acc1, A1.z, W2v); fma4(acc1, A1.w, W3v);
        }
        float4 bi1 = *(const float4*)&b1[4 * tx];
        #pragma unroll
        for (int r = 0; r < 2; ++r) {
            float4 a = r ? acc1 : acc0;
            float v0 = a.x + bi1.x; v0 = v0 > 0.f ? v0 : 0.f;
            float v1 = a.y + bi1.y; v1 = v1 > 0.f ? v1 : 0.f;
            float v2 = a.z + bi1.z; v2 = v2 > 0.f ? v2 : 0.f;
            float v3 = a.w + bi1.w; v3 = v3 > 0.f ? v3 : 0.f;
            *(float4*)&Gr[(ty + 16 * r) * 68 + 4 * tx] = make_float4(v0, v1, v2, v3);
        }
    }

    // GEMM2 per 64-col chunk: gate = sigmoid(Gr @ W2[:,chunk] + b2)
    for (int ch = 0; ch < 4; ++ch) {
        __syncthreads();   // GEMM1 Ws reads / prev chunk reads done
        #pragma unroll
        for (int i = 0; i < 4; ++i) {
            int f4 = t + i * 256;
            int row = f4 >> 4, col = (f4 & 15) * 4;
            *(float4*)&Ws[row * 68 + col] =
                *(const float4*)&W2[(size_t)row * 256 + ch * 64 + col];
        }
        __syncthreads();
        float4 acc0 = make_float4(0.f,0.f,0.f,0.f), acc1 = make_float4(0.f,0.f,0.f,0.f);
        #pragma unroll 8
        for (int k4 = 0; k4 < 64; k4 += 4) {
            float4 A0 = *(const float4*)&Gr[ty * 68 + k4];
            float4 A1 = *(const float4*)&Gr[(ty + 16) * 68 + k4];
            float4 W0 = *(const float4*)&Ws[(k4 + 0) * 68 + 4 * tx];
            float4 W1v = *(const float4*)&Ws[(k4 + 1) * 68 + 4 * tx];
            float4 W2v = *(const float4*)&Ws[(k4 + 2) * 68 + 4 * tx];
            float4 W3v = *(const float4*)&Ws[(k4 + 3) * 68 + 4 * tx];
            fma4(acc0, A0.x, W0); fma4(acc0, A0.y, W1v); fma4(acc0, A0.z, W2v); fma4(acc0, A0.w, W3v);
            fma4(acc1, A1.x, W0); fma4(acc1, A1.y, W1v); fma4(acc1, A1.z, W2v); fma4(acc1, A1.w, W3v);
        }
        float4 bi2 = *(const float4*)&b2[ch * 64 + 4 * tx];
        #pragma unroll
        for (int r = 0; r < 2; ++r) {
            float4 a = r ? acc1 : acc0;
            int m = m0 + ty + 16 * r;
            float g0 = 1.f / (1.f + expf(-(a.x + bi2.x)));
            float g1 = 1.f / (1.f + expf(-(a.y + bi2.y)));
            float g2 = 1.f / (1.f + expf(-(a.z + bi2.z)));
            float g3 = 1.f / (1.f + expf(-(a.w + bi2.w)));
            *(float4*)&gate[(size_t)m * 256 + ch * 64 + 4 * tx] = make_float4(g0, g1, g2, g3);
        }
    }
}

// ---------------------------------------------------------------------------
// K2: layer 1, both stacks, TWO checkpoints per dispatch (grid 1312).
// g_init bf16; G1 out bf16 into per-checkpoint slot (it&1).
__global__ __launch_bounds__(256, 4) void k_layer1(
    const int*   __restrict__ cnt,    // [2N]  adj rows 0..N, pea rows N..2N
    const int*   __restrict__ cols,   // [2N][NNZCAP]
    const float* __restrict__ vals,
    const ushort* __restrict__ g_init4, // [4][M][64] bf16
    int it0,
    const float* __restrict__ wadj, const float* __restrict__ badj,
    const float* __restrict__ wpea, const float* __restrict__ bpea,
    ushort* __restrict__ G1a4, ushort* __restrict__ G1p4)   // [2][M][256] bf16
{
    __shared__ float Ma[32 * 68];
    __shared__ float Mp[32 * 68];
    __shared__ float Ws[64 * 68];
    int t = threadIdx.x, lane = t & 63, w = t >> 6;
    int itk = blockIdx.x / 656;
    int lx  = blockIdx.x - itk * 656;
    int vb = (lx & 7) * 82 + (lx >> 3);   // XCD swizzle
    if (vb >= 650) return;
    int m0 = vb * 32;
    const ushort* g_init = g_init4 + (size_t)(it0 + itk) * M_ * H_;
    ushort* G1a = G1a4 + (size_t)itk * M_ * 256;
    ushort* G1p = G1p4 + (size_t)itk * M_ * 256;

    // ---- gather: lane=(rr,cl); rows w*8+rr and w*8+4+rr, both stacks ----
    {
        int cl = lane & 15, rr = lane >> 4;
        int mA = m0 + w * 8 + rr;
        int mB = mA + 4;
        int nA = mA % N_, nB = mB % N_;
        const ushort* gA = g_init + (size_t)(mA - nA) * H_ + cl * 4;
        const ushort* gB = g_init + (size_t)(mB - nB) * H_ + cl * 4;
        const int   *cA0 = cols + nA * NNZCAP,        *cB0 = cols + nB * NNZCAP;
        const float *vA0 = vals + nA * NNZCAP,        *vB0 = vals + nB * NNZCAP;
        const int   *cA1 = cols + (N_ + nA) * NNZCAP, *cB1 = cols + (N_ + nB) * NNZCAP;
        const float *vA1 = vals + (N_ + nA) * NNZCAP, *vB1 = vals + (N_ + nB) * NNZCAP;
        int jm = max(max(cnt[nA], cnt[nB]), max(cnt[N_ + nA], cnt[N_ + nB]));
        float4 aA0 = make_float4(0.f,0.f,0.f,0.f), aB0 = make_float4(0.f,0.f,0.f,0.f);
        float4 aA1 = make_float4(0.f,0.f,0.f,0.f), aB1 = make_float4(0.f,0.f,0.f,0.f);
        for (int j = 0; j < jm; j += 2) {     // zero-padded -> branch-free
            fma4(aA0, vA0[j],   unpack_bf4(*(const uint2*)&gA[cA0[j]   * H_]));
            fma4(aA0, vA0[j+1], unpack_bf4(*(const uint2*)&gA[cA0[j+1] * H_]));
            fma4(aB0, vB0[j],   unpack_bf4(*(const uint2*)&gB[cB0[j]   * H_]));
            fma4(aB0, vB0[j+1], unpack_bf4(*(const uint2*)&gB[cB0[j+1] * H_]));
            fma4(aA1, vA1[j],   unpack_bf4(*(const uint2*)&gA[cA1[j]   * H_]));
            fma4(aA1, vA1[j+1], unpack_bf4(*(const uint2*)&gA[cA1[j+1] * H_]));
            fma4(aB1, vB1[j],   unpack_bf4(*(const uint2*)&gB[cB1[j]   * H_]));
            fma4(aB1, vB1[j+1], unpack_bf4(*(const uint2*)&gB[cB1[j+1] * H_]));
        }
        *(float4*)&Ma[(w * 8 + rr) * 68 + cl * 4]     = aA0;
        *(float4*)&Ma[(w * 8 + 4 + rr) * 68 + cl * 4] = aB0;
        *(float4*)&Mp[(w * 8 + rr) * 68 + cl * 4]     = aA1;
        *(float4*)&Mp[(w * 8 + 4 + rr) * 68 + cl * 4] = aB1;
    }

    int tx = t & 15, ty = t >> 4;
    for (int sc = 0; sc < 8; ++sc) {
        int stack = sc >> 2, c = sc & 3;
        const float* wb0 = (stack ? wpea : wadj) + (size_t)c * 16384;   // layer 0
        const float* wb1 = wb0 + 4096;
        __syncthreads();   // gather done (sc=0) / prev Ws reads done (sc>0)
        #pragma unroll
        for (int i = 0; i < 4; ++i) {
            int f4 = t + i * 256;
            int row = f4 >> 4, col = (f4 & 15) * 4;
            float4 x0 = *(const float4*)&wb0[row * 64 + col];
            float4 x1 = *(const float4*)&wb1[row * 64 + col];
            *(float4*)&Ws[row * 68 + col] = make_float4(x0.x + x1.x, x0.y + x1.y,
                                                        x0.z + x1.z, x0.w + x1.w);
        }
        __syncthreads();

        const float* Msrc = stack ? Mp : Ma;
        float4 acc0 = make_float4(0.f, 0.f, 0.f, 0.f);
        float4 acc1 = make_float4(0.f, 0.f, 0.f, 0.f);
        #pragma unroll 8
        for (int k4 = 0; k4 < 64; k4 += 4) {
            float4 A0 = *(const float4*)&Msrc[ty * 68 + k4];
            float4 A1 = *(const float4*)&Msrc[(ty + 16) * 68 + k4];
            float4 W0 = *(const float4*)&Ws[(k4 + 0) * 68 + 4 * tx];
            float4 W1 = *(const float4*)&Ws[(k4 + 1) * 68 + 4 * tx];
            float4 W2 = *(const float4*)&Ws[(k4 + 2) * 68 + 4 * tx];
            float4 W3 = *(const float4*)&Ws[(k4 + 3) * 68 + 4 * tx];
            fma4(acc0, A0.x, W0); fma4(acc0, A0.y, W1); fma4(acc0, A0.z, W2); fma4(acc0, A0.w, W3);
            fma4(acc1, A1.x, W0); fma4(acc1, A1.y, W1); fma4(acc1, A1.z, W2); fma4(acc1, A1.w, W3);
        }
        const float* bias = (stack ? bpea : badj) + c * L_ * H_;   // layer 0
        float4 bi = *(const float4*)&bias[4 * tx];
        ushort* Gout = stack ? G1p : G1a;
        #pragma unroll
        for (int r = 0; r < 2; ++r) {
            float4 a = r ? acc1 : acc0;
            float v0 = a.x + bi.x; v0 = v0 > 0.f ? v0 : 0.f;
            float v1 = a.y + bi.y; v1 = v1 > 0.f ? v1 : 0.f;
            float v2 = a.z + bi.z; v2 = v2 > 0.f ? v2 : 0.f;
            float v3 = a.w + bi.w; v3 = v3 > 0.f ? v3 : 0.f;
            *(uint2*)&Gout[(size_t)(m0 + ty + 16 * r) * 256 + c * 64 + 4 * tx] =
                pack_bf4(make_float4(v0, v1, v2, v3));
        }
    }
}

// ---------------------------------------------------------------------------
// K3: layer 2 + gate mix + reduce GEMM + partial sums, all fused (R11-proven).
__global__ __launch_bounds__(256, 3) void k_mix(
    const int*   __restrict__ cnt,
    const int*   __restrict__ cols,
    const float* __restrict__ vals,
    const ushort* __restrict__ G1a, const ushort* __restrict__ G1p,  // [M][256] bf16
    const float* __restrict__ wadj, const float* __restrict__ badj,
    const float* __restrict__ wpea, const float* __restrict__ bpea,
    const float* __restrict__ gate,     // [M][256]
    const float* __restrict__ reduce_w, // [256][64]
    const float* __restrict__ reduce_b, // [64]
    const float* __restrict__ residual, // [M][64]
    float* __restrict__ cr,             // [M][64]
    float* __restrict__ partials)       // [2*650]
{
    __shared__ float Mt[32 * 260];
    __shared__ float Ws[64 * 68];
    int t = threadIdx.x, lane = t & 63, w = t >> 6;
    int vb = (blockIdx.x & 7) * 82 + (blockIdx.x >> 3);   // XCD swizzle
    if (vb >= 650) return;
    int m0 = vb * 32;
    int tx = t & 15, ty = t >> 4;

    float4 res[4][2];   // gate*relu(adj) -> then full mix, carried in regs
    float4 gsv[4][2];   // saved gate

    // ======== stack A gather: 2 rows x unroll 2, bf16 unpack ========
    for (int pp = 0; pp < 8; pp += 2) {
        int ma = m0 + w * 8 + pp, mb = ma + 1;
        int na = ma % N_, nb = mb % N_;
        const ushort* ga = G1a + (size_t)(ma - na) * 256 + lane * 4;
        const ushort* gb = G1a + (size_t)(mb - nb) * 256 + lane * 4;
        const int   *cap = cols + na * NNZCAP, *cbp = cols + nb * NNZCAP;
        const float *vap = vals + na * NNZCAP, *vbp = vals + nb * NNZCAP;
        int jm = max(cnt[na], cnt[nb]);
        float4 a0 = make_float4(0.f,0.f,0.f,0.f), a1 = make_float4(0.f,0.f,0.f,0.f);
        for (int j = 0; j < jm; j += 2) {     // zero-padded -> branch-free
            float w00 = vap[j], w01 = vap[j+1];
            float w10 = vbp[j], w11 = vbp[j+1];
            float4 x00 = unpack_bf4(*(const uint2*)&ga[cap[j]   * 256]);
            float4 x01 = unpack_bf4(*(const uint2*)&ga[cap[j+1] * 256]);
            float4 x10 = unpack_bf4(*(const uint2*)&gb[cbp[j]   * 256]);
            float4 x11 = unpack_bf4(*(const uint2*)&gb[cbp[j+1] * 256]);
            fma4(a0, w00, x00); fma4(a0, w01, x01);
            fma4(a1, w10, x10); fma4(a1, w11, x11);
        }
        *(float4*)&Mt[(w * 8 + pp) * 260 + lane * 4]     = a0;
        *(float4*)&Mt[(w * 8 + pp + 1) * 260 + lane * 4] = a1;
    }

    #pragma unroll
    for (int c = 0; c < 4; ++c) {
        __syncthreads();
        const float* w0 = wadj + (size_t)c * 16384 + 8192;   // layer 1
        const float* w1 = w0 + 4096;
        #pragma unroll
        for (int i = 0; i < 4; ++i) {
            int f4 = t + i * 256;
            int row = f4 >> 4, col = (f4 & 15) * 4;
            float4 x0 = *(const float4*)&w0[row * 64 + col];
            float4 x1 = *(const float4*)&w1[row * 64 + col];
            *(float4*)&Ws[row * 68 + col] = make_float4(x0.x + x1.x, x0.y + x1.y,
                                                        x0.z + x1.z, x0.w + x1.w);
        }
        __syncthreads();
        float4 acc0 = make_float4(0.f,0.f,0.f,0.f), acc1 = make_float4(0.f,0.f,0.f,0.f);
        #pragma unroll 8
        for (int k4 = 0; k4 < 64; k4 += 4) {
            float4 A0 = *(const float4*)&Mt[ty * 260 + c * 64 + k4];
            float4 A1 = *(const float4*)&Mt[(ty + 16) * 260 + c * 64 + k4];
            float4 W0 = *(const float4*)&Ws[(k4 + 0) * 68 + 4 * tx];
            float4 W1 = *(const float4*)&Ws[(k4 + 1) * 68 + 4 * tx];
            float4 W2 = *(const float4*)&Ws[(k4 + 2) * 68 + 4 * tx];
            float4 W3 = *(const float4*)&Ws[(k4 + 3) * 68 + 4 * tx];
            fma4(acc0, A0.x, W0); fma4(acc0, A0.y, W1); fma4(acc0, A0.z, W2); fma4(acc0, A0.w, W3);
            fma4(acc1, A1.x, W0); fma4(acc1, A1.y, W1); fma4(acc1, A1.z, W2); fma4(acc1, A1.w, W3);
        }
        float4 bA = *(const float4*)&badj[(c * L_ + 1) * H_ + 4 * tx];
        #pragma unroll
        for (int r = 0; r < 2; ++r) {
            float4 a = r ? acc1 : acc0;
            float v0 = a.x + bA.x; v0 = v0 > 0.f ? v0 : 0.f;
            float v1 = a.y + bA.y; v1 = v1 > 0.f ? v1 : 0.f;
            float v2 = a.z + bA.z; v2 = v2 > 0.f ? v2 : 0.f;
            float v3 = a.w + bA.w; v3 = v3 > 0.f ? v3 : 0.f;
            size_t o = (size_t)(m0 + ty + 16 * r) * 256 + c * 64 + 4 * tx;
            float4 g = *(const float4*)&gate[o];
            gsv[c][r] = g;
            res[c][r] = make_float4(g.x * v0, g.y * v1, g.z * v2, g.w * v3);
        }
    }

    // ======== stack P: re-gather, mix into registers, commit to Mt ========
    __syncthreads();   // all Mt reads done before overwrite
    for (int pp = 0; pp < 8; pp += 2) {
        int ma = m0 + w * 8 + pp, mb = ma + 1;
        int na = ma % N_, nb = mb % N_;
        const ushort* ga = G1p + (size_t)(ma - na) * 256 + lane * 4;
        const ushort* gb = G1p + (size_t)(mb - nb) * 256 + lane * 4;
        const int   *cap = cols + (N_ + na) * NNZCAP, *cbp = cols + (N_ + nb) * NNZCAP;
        const float *vap = vals + (N_ + na) * NNZCAP, *vbp = vals + (N_ + nb) * NNZCAP;
        int jm = max(cnt[N_ + na], cnt[N_ + nb]);
        float4 a0 = make_float4(0.f,0.f,0.f,0.f), a1 = make_float4(0.f,0.f,0.f,0.f);
        for (int j = 0; j < jm; j += 2) {
            float w00 = vap[j], w01 = vap[j+1];
            float w10 = vbp[j], w11 = vbp[j+1];
            float4 x00 = unpack_bf4(*(const uint2*)&ga[cap[j]   * 256]);
            float4 x01 = unpack_bf4(*(const uint2*)&ga[cap[j+1] * 256]);
            float4 x10 = unpack_bf4(*(const uint2*)&gb[cbp[j]   * 256]);
            float4 x11 = unpack_bf4(*(const uint2*)&gb[cbp[j+1] * 256]);
            fma4(a0, w00, x00); fma4(a0, w01, x01);
            fma4(a1, w10, x10); fma4(a1, w11, x11);
        }
        *(float4*)&Mt[(w * 8 + pp) * 260 + lane * 4]     = a0;
        *(float4*)&Mt[(w * 8 + pp + 1) * 260 + lane * 4] = a1;
    }

    #pragma unroll
    for (int c = 0; c < 4; ++c) {
        __syncthreads();   // prev GEMM's slice reads done -> safe to commit c-1
        if (c > 0) {
            *(float4*)&Mt[ty * 260 + (c - 1) * 64 + 4 * tx]        = res[c - 1][0];
            *(float4*)&Mt[(ty + 16) * 260 + (c - 1) * 64 + 4 * tx] = res[c - 1][1];
        }
        const float* w0 = wpea + (size_t)c * 16384 + 8192;   // layer 1
        const float* w1 = w0 + 4096;
        #pragma unroll
        for (int i = 0; i < 4; ++i) {
            int f4 = t + i * 256;
            int row = f4 >> 4, col = (f4 & 15) * 4;
            float4 x0 = *(const float4*)&w0[row * 64 + col];
            float4 x1 = *(const float4*)&w1[row * 64 + col];
            *(float4*)&Ws[row * 68 + col] = make_float4(x0.x + x1.x, x0.y + x1.y,
                                                        x0.z + x1.z, x0.w + x1.w);
        }
        __syncthreads();
        float4 acc0 = make_float4(0.f,0.f,0.f,0.f), acc1 = make_float4(0.f,0.f,0.f,0.f);
        #pragma unroll 8
        for (int k4 = 0; k4 < 64; k4 += 4) {
            float4 A0 = *(const float4*)&Mt[ty * 260 + c * 64 + k4];
            float4 A1 = *(const float4*)&Mt[(ty + 16) * 260 + c * 64 + k4];
            float4 W0 = *(const float4*)&Ws[(k4 + 0) * 68 + 4 * tx];
            float4 W1 = *(const float4*)&Ws[(k4 + 1) * 68 + 4 * tx];
            float4 W2 = *(const float4*)&Ws[(k4 + 2) * 68 + 4 * tx];
            float4 W3 = *(const float4*)&Ws[(k4 + 3) * 68 + 4 * tx];
            fma4(acc0, A0.x, W0); fma4(acc0, A0.y, W1); fma4(acc0, A0.z, W2); fma4(acc0, A0.w, W3);
            fma4(acc1, A1.x, W0); fma4(acc1, A1.y, W1); fma4(acc1, A1.z, W2); fma4(acc1, A1.w, W3);
        }
        float4 bP = *(const float4*)&bpea[(c * L_ + 1) * H_ + 4 * tx];
        #pragma unroll
        for (int r = 0; r < 2; ++r) {
            float4 p = r ? acc1 : acc0;
            float v0 = p.x + bP.x; v0 = v0 > 0.f ? v0 : 0.f;
            float v1 = p.y + bP.y; v1 = v1 > 0.f ? v1 : 0.f;
            float v2 = p.z + bP.z; v2 = v2 > 0.f ? v2 : 0.f;
            float v3 = p.w + bP.w; v3 = v3 > 0.f ? v3 : 0.f;
            float4 g  = gsv[c][r];
            float4 rr = res[c][r];
            res[c][r] = make_float4(rr.x + (1.f - g.x) * v0,
                                    rr.y + (1.f - g.y) * v1,
                                    rr.z + (1.f - g.z) * v2,
                                    rr.w + (1.f - g.w) * v3);
        }
    }
    __syncthreads();   // last GEMM's slice-3 reads done
    *(float4*)&Mt[ty * 260 + 3 * 64 + 4 * tx]        = res[3][0];
    *(float4*)&Mt[(ty + 16) * 260 + 3 * 64 + 4 * tx] = res[3][1];

    // ======== reduce GEMM: cr = Mt[32x256] @ reduce_w + bias + residual ======
    float4 racc0 = make_float4(0.f,0.f,0.f,0.f), racc1 = make_float4(0.f,0.f,0.f,0.f);
    for (int kk = 0; kk < 4; ++kk) {
        __syncthreads();   // Mt commits visible (kk=0) / prev Ws reads done
        #pragma unroll
        for (int i = 0; i < 4; ++i) {
            int f4 = t + i * 256;
            int row = f4 >> 4, col = (f4 & 15) * 4;
            *(float4*)&Ws[row * 68 + col] =
                *(const float4*)&reduce_w[(size_t)(kk * 64 + row) * 64 + col];
        }
        __syncthreads();
        #pragma unroll 8
        for (int k4 = 0; k4 < 64; k4 += 4) {
            float4 A0 = *(const float4*)&Mt[ty * 260 + kk * 64 + k4];
            float4 A1 = *(const float4*)&Mt[(ty + 16) * 260 + kk * 64 + k4];
            float4 W0 = *(const float4*)&Ws[(k4 + 0) * 68 + 4 * tx];
            float4 W1 = *(const float4*)&Ws[(k4 + 1) * 68 + 4 * tx];
            float4 W2 = *(const float4*)&Ws[(k4 + 2) * 68 + 4 * tx];
            float4 W3 = *(const float4*)&Ws[(k4 + 3) * 68 + 4 * tx];
            fma4(racc0, A0.x, W0); fma4(racc0, A0.y, W1); fma4(racc0, A0.z, W2); fma4(racc0, A0.w, W3);
            fma4(racc1, A1.x, W0); fma4(racc1, A1.y, W1); fma4(racc1, A1.z, W2); fma4(racc1, A1.w, W3);
        }
    }
    float4 bi = *(const float4*)&reduce_b[4 * tx];
    float s = 0.f, s2 = 0.f;
    #pragma unroll
    for (int r = 0; r < 2; ++r) {
        int m = m0 + ty + 16 * r;
        float4 a = r ? racc1 : racc0;
        float4 rv = *(const float4*)&residual[(size_t)m * 64 + 4 * tx];
        float v0 = a.x + bi.x + rv.x;
        float v1 = a.y + bi.y + rv.y;
        float v2 = a.z + bi.z + rv.z;
        float v3 = a.w + bi.w + rv.w;
        *(float4*)&cr[(size_t)m * 64 + 4 * tx] = make_float4(v0, v1, v2, v3);
        s += v0 + v1 + v2 + v3;
        s2 += v0 * v0 + v1 * v1 + v2 * v2 + v3 * v3;
    }
    __syncthreads();   // Ws reads done; reuse as reduction scratch
    float* r1 = Ws;
    float* r2 = Ws + 256;
    r1[t] = s; r2[t] = s2;
    __syncthreads();
    for (int off = 128; off > 0; off >>= 1) {
        if (t < off) { r1[t] += r1[t + off]; r2[t] += r2[t + off]; }
        __syncthreads();
    }
    if (t == 0) { partials[vb] = r1[0]; partials[650 + vb] = r2[0]; }
}

// ---------------------------------------------------------------------------
// K5: out = relu(ocw*norm(cr) + ocb) @ olw + olb. One wave per 64 rows
// (grid 325) with float4 row loads; LN reduce via wave shuffles.
__global__ __launch_bounds__(64) void k_out(
    const float* __restrict__ cr, const float* __restrict__ partials,
    const float* __restrict__ ocw, const float* __restrict__ ocb,
    const float* __restrict__ olw, const float* __restrict__ olb,
    float* __restrict__ out) {
    int t = threadIdx.x;
    float a = 0.f, b2s = 0.f;
    for (int i = t; i < 650; i += 64) { a += partials[i]; b2s += partials[650 + i]; }
    #pragma unroll
    for (int off = 32; off > 0; off >>= 1) {
        a   += __shfl_xor(a, off);
        b2s += __shfl_xor(b2s, off);
    }
    const float inv = 1.f / (float)(M_ * H_);
    float mu  = a * inv;
    float var = b2s * inv - mu * mu;
    float rs  = rsqrtf(var + 1e-5f);

    int m = blockIdx.x * 64 + t;          // M = 325*64 exactly
    int b = m / N_, n = m % N_;
    float cw[P_], cb[P_], acc[P_];
    #pragma unroll
    for (int p = 0; p < P_; ++p) { cw[p] = ocw[p]; cb[p] = ocb[p]; acc[p] = 0.f; }
    const float* lr = cr + (size_t)m * H_;
    for (int h4 = 0; h4 < 64; h4 += 4) {
        float4 lv4 = *(const float4*)&lr[h4];
        float4 wv4 = *(const float4*)&olw[h4];
        float lv[4] = {(lv4.x - mu) * rs, (lv4.y - mu) * rs,
                       (lv4.z - mu) * rs, (lv4.w - mu) * rs};
        float wv[4] = {wv4.x, wv4.y, wv4.z, wv4.w};
        #pragma unroll
        for (int e = 0; e < 4; ++e) {
            float lvv = lv[e], wvv = wv[e];
            #pragma unroll
            for (int p = 0; p < P_; ++p) {
                float u = cw[p] * lvv + cb[p];
                u = u > 0.f ? u : 0.f;
                acc[p] += u * wvv;
            }
        }
    }
    float ob = olb[0];
    #pragma unroll
    for (int p = 0; p < P_; ++p)
        out[(size_t)(b * P_ + p) * N_ + n] = acc[p] + ob;
}

// ---------------------------------------------------------------------------
extern "C" void kernel_launch(void* const* d_in, const int* in_sizes, int n_in,
                              void* d_out, int out_size, void* d_ws, size_t ws_size,
                              hipStream_t stream) {
    const float* inp      = (const float*)d_in[0];
    const float* adj_fwd  = (const float*)d_in[1];
    const float* pea_fwd  = (const float*)d_in[3];
    const float* w_in     = (const float*)d_in[5];
    const float* b_in     = (const float*)d_in[6];
    const float* res_w    = (const float*)d_in[7];
    const float* res_b    = (const float*)d_in[8];
    const float* gconv_w  = (const float*)d_in[9];
    const float* gconv_b  = (const float*)d_in[10];
    const float* gate1_w  = (const float*)d_in[11];
    const float* gate1_b  = (const float*)d_in[12];
    const float* gate2_w  = (const float*)d_in[13];
    const float* gate2_b  = (const float*)d_in[14];
    const float* reduce_w = (const float*)d_in[15];
    const float* reduce_b = (const float*)d_in[16];
    const float* gadj_w   = (const float*)d_in[17];
    const float* gadj_b   = (const float*)d_in[18];
    const float* gpea_w   = (const float*)d_in[19];
    const float* gpea_b   = (const float*)d_in[20];
    const float* ocw      = (const float*)d_in[21];
    const float* ocb      = (const float*)d_in[22];
    const float* olw      = (const float*)d_in[23];
    const float* olb      = (const float*)d_in[24];
    float* out = (float*)d_out;

    // workspace layout — fp32 region then bf16 buffers (~86 MB total)
    float* ws       = (float*)d_ws;
    float* gate     = ws;                              // M*256
    float* residual = gate + (size_t)M_ * 256;         // M*64
    float* cr       = residual + (size_t)M_ * H_;      // M*64
    float* partials = cr + (size_t)M_ * H_;            // 1300
    int*   scnt  = (int*)(partials + 1300);            // 2*325
    int*   scols = scnt + 2 * N_;                      // 2*325*64
    float* svals = (float*)(scols + 2 * N_ * NNZCAP);  // 2*325*64
    ushort* G1a4 = (ushort*)(svals + 2 * N_ * NNZCAP); // 2 slots x M*256 bf16
    ushort* G1p4 = G1a4 + 2 * (size_t)M_ * 256;        // 2 slots x M*256 bf16
    ushort* g_init4 = G1p4 + 2 * (size_t)M_ * 256;     // 4 x M*64 bf16

    k_build_sparse<<<N_, 64, 0, stream>>>(adj_fwd, scnt,      scols,              svals);
    k_build_sparse<<<N_, 64, 0, stream>>>(pea_fwd, scnt + N_, scols + N_*NNZCAP,  svals + N_*NNZCAP);
    k_ginit<<<(4 * M_ * H_) / 256, 256, 0, stream>>>(inp, w_in, b_in, g_init4);

    for (int half = 0; half < 2; ++half) {
        // layer 1 for checkpoints {2*half, 2*half+1} in one batched dispatch
        k_layer1<<<2 * 656, 256, 0, stream>>>(
            scnt, scols, svals, g_init4, half * 2,
            gadj_w, gadj_b, gpea_w, gpea_b, G1a4, G1p4);
        for (int it = half * 2; it < half * 2 + 2; ++it) {
            k_gate<<<M_ / 32, 256, 0, stream>>>(
                inp, w_in, b_in, gconv_w, gconv_b, res_w, res_b, cr, partials, it,
                gate1_w, gate1_b, gate2_w, gate2_b, residual, gate);
            int slot = it & 1;
            k_mix<<<656, 256, 0, stream>>>(
                scnt, scols, svals,
                G1a4 + (size_t)slot * M_ * 256, G1p4 + (size_t)slot * M_ * 256,
                gadj_w, gadj_b, gpea_w, gpea_b, gate,
                reduce_w, reduce_b, residual, cr, partials);
        }
    }

    k_out<<<N_, 64, 0, stream>>>(cr, partials, ocw, ocb, olw, olb, out);
}

// Round 17
// 657.968 us; speedup vs baseline: 1.5298x; 1.0781x over previous
//
#include <hip/hip_runtime.h>
#include <hip/hip_bf16.h>
#include <math.h>

// Problem constants
#define B_    64
#define T_    13
#define N_    325
#define H_    64
#define C_    4
#define L_    2
#define S_    4
#define P_    12
#define KCP   4            // checkpoints [4,7,10,13]
#define M_    (B_*N_)      // 20800 (= 650*32 exactly)
#define ADJLD 1300         // leading dim of combined adjacency inputs
#define NNZCAP 64          // max nonzeros per adjacency row (3% density -> mean ~10)
#define WPITCH 72          // ushort pitch for transposed W tiles (144B rows, 16B-aligned frags)

typedef short bfrag __attribute__((ext_vector_type(8)));   // 8 bf16 = 4 VGPRs
typedef float f32x4 __attribute__((ext_vector_type(4)));

__device__ __forceinline__ void fma4(float4& a, float s, float4 x) {
    a.x += s * x.x; a.y += s * x.y; a.z += s * x.z; a.w += s * x.w;
}
// bf16 pack (RNE) / unpack helpers
__device__ __forceinline__ ushort bf_rne(float f) {
    unsigned u = __float_as_uint(f);
    return (ushort)((u + 0x7fffu + ((u >> 16) & 1u)) >> 16);
}
__device__ __forceinline__ uint2 pack_bf4(float4 v) {
    unsigned a = __float_as_uint(v.x), b = __float_as_uint(v.y);
    unsigned c = __float_as_uint(v.z), d = __float_as_uint(v.w);
    a = (a + 0x7fffu + ((a >> 16) & 1u)) >> 16;
    b = (b + 0x7fffu + ((b >> 16) & 1u)) >> 16;
    c = (c + 0x7fffu + ((c >> 16) & 1u)) >> 16;
    d = (d + 0x7fffu + ((d >> 16) & 1u)) >> 16;
    return make_uint2(a | (b << 16), c | (d << 16));
}
__device__ __forceinline__ float4 unpack_bf4(uint2 p) {
    return make_float4(__uint_as_float(p.x << 16),
                       __uint_as_float(p.x & 0xffff0000u),
                       __uint_as_float(p.y << 16),
                       __uint_as_float(p.y & 0xffff0000u));
}

// ---------------------------------------------------------------------------
// Build padded sparse rows (column-ordered, deterministic). One wave per row.
__global__ void k_build_sparse(const float* __restrict__ A,
                               int* __restrict__ cnt, int* __restrict__ cols,
                               float* __restrict__ vals) {
    int n    = blockIdx.x;
    int lane = threadIdx.x;
    const float* row = A + (size_t)n * ADJLD;
    int c = 0;
    for (int c0 = 0; c0 < 384; c0 += 64) {
        int col = c0 + lane;
        float v = (col < N_) ? row[col] : 0.f;
        unsigned long long m = __ballot(v != 0.f);
        int idx = c + __popcll(m & ((1ull << lane) - 1ull));
        if (v != 0.f && idx < NNZCAP) {
            cols[n * NNZCAP + idx] = col;
            vals[n * NNZCAP + idx] = v;
        }
        c += __popcll(m);
    }
    if (c + lane < NNZCAP) {                 // zero-pad tail -> branch-free consumers
        cols[n * NNZCAP + c + lane] = 0;
        vals[n * NNZCAP + c + lane] = 0.f;
    }
    if (lane == 0) cnt[n] = (c < NNZCAP) ? c : NNZCAP;
}

// ---------------------------------------------------------------------------
// K0: g_init for ALL checkpoints (last-independent): x[:, 3it+3] @ w_in + b_in
__global__ void k_ginit(const float* __restrict__ inp,
                        const float* __restrict__ w_in, const float* __restrict__ b_in,
                        ushort* __restrict__ g_init4) {     // [4][M][64] bf16
    int idx = blockIdx.x * 256 + threadIdx.x;   // over 4*M*H = 5,324,800
    if (idx >= 4 * M_ * H_) return;
    int h  = idx & 63;
    int r  = idx >> 6;           // it*M + m
    int it = r / M_;
    int m  = r - it * M_;
    int b  = m / N_, n = m % N_;
    int tt = 3 * it + 3;
    const float* ip = inp + ((size_t)(b * T_ + tt) * N_ + n) * 2;
    g_init4[idx] = bf_rne(ip[0] * w_in[h] + ip[1] * w_in[H_ + h] + b_in[h]);
}

// ---------------------------------------------------------------------------
// Prep: transpose + bf16-pack LAYER-0 W01 mats (8: stack*4+c).
// WT[mat][n][k] = W0[k][n]+W1[k][n], pitch WPITCH.
__global__ void k_prep_w(const float* __restrict__ gadj_w,
                         const float* __restrict__ gpea_w,
                         ushort* __restrict__ WT) {
    int mat = blockIdx.x;                       // 0..7
    int stack = mat >> 2, c = mat & 3;
    const float* w0 = (stack ? gpea_w : gadj_w) + (size_t)(c * L_ * 2) * 4096;  // layer 0
    const float* w1 = w0 + 4096;
    for (int i = 0; i < 16; ++i) {
        int e = threadIdx.x + i * 256;          // e = k*64 + n
        int k = e >> 6, n = e & 63;
        WT[((size_t)mat * 64 + n) * WPITCH + k] = bf_rne(w0[e] + w1[e]);
    }
}

// ---------------------------------------------------------------------------
// K1: fused [norm of prev cr] + gf/residual + 2-layer gate MLP. 32-row tiles.
__global__ __launch_bounds__(256, 3) void k_gate(
    const float* __restrict__ inp,
    const float* __restrict__ w_in, const float* __restrict__ b_in,
    const float* __restrict__ gconv_w, const float* __restrict__ gconv_b,
    const float* __restrict__ res_w,   const float* __restrict__ res_b,
    const float* __restrict__ cr, const float* __restrict__ partials, int it,
    const float* __restrict__ W1, const float* __restrict__ b1,
    const float* __restrict__ W2, const float* __restrict__ b2,
    float* __restrict__ residual,
    float* __restrict__ gate)
{
    __shared__ float Gf[32 * 68];
    __shared__ float Ws[64 * 68];
    __shared__ float Gr[32 * 68];
    int t = threadIdx.x, lane = t & 63, w = t >> 6;
    int m0 = blockIdx.x * 32;

    // ---- phase -1: LayerNorm constants from partials (it>0, 650 blocks) ----
    float mu = 0.f, rs = 0.f;
    if (it > 0) {
        float a = 0.f, b = 0.f;
        for (int i = t; i < 650; i += 256) { a += partials[i]; b += partials[650 + i]; }
        Ws[t] = a; Ws[256 + t] = b;
        __syncthreads();
        for (int off = 128; off > 0; off >>= 1) {
            if (t < off) { Ws[t] += Ws[t + off]; Ws[256 + t] += Ws[256 + t + off]; }
            __syncthreads();
        }
        const float inv = 1.f / (float)(M_ * H_);
        mu = Ws[0] * inv;
        float var = Ws[256] * inv - mu * mu;
        rs = rsqrtf(var + 1e-5f);
        __syncthreads();   // reduction reads done before W1 staging overwrites Ws
    }

    // ---- phase 0: gf / residual (32 rows, 8 per wave) ----
    {
        float wa = w_in[lane], wb = w_in[H_ + lane], bi = b_in[lane];
        float gw0 = gconv_w[0], gw1 = gconv_w[1], gw2 = gconv_w[2], gw3 = gconv_w[3];
        float rw0 = res_w[0],   rw1 = res_w[1],   rw2 = res_w[2],   rw3 = res_w[3];
        float gb = gconv_b[0],  rb = res_b[0];
        int left = (it == 0) ? 0 : (3 * it + 1);
        for (int i = 0; i < 8; ++i) {
            int r = i * 4 + w;                  // wave-uniform row
            int m = m0 + r;
            int b = m / N_, n = m % N_;
            const float* ipb = inp + ((size_t)b * T_ * N_ + n) * 2;
            float v0;
            if (it > 0) v0 = (cr[(size_t)m * H_ + lane] - mu) * rs;
            else        { v0 = ipb[0] * wa + ipb[1] * wb + bi; }
            int t1 = (it == 0) ? 1 : left;
            const float* ip1 = ipb + (size_t)t1 * N_ * 2;
            const float* ip2 = ip1 + (size_t)N_ * 2;
            const float* ip3 = ip2 + (size_t)N_ * 2;
            float v1 = ip1[0] * wa + ip1[1] * wb + bi;
            float v2 = ip2[0] * wa + ip2[1] * wb + bi;
            float v3 = ip3[0] * wa + ip3[1] * wb + bi;
            Gf[r * 68 + lane] = gb + gw0 * v0 + gw1 * v1 + gw2 * v2 + gw3 * v3;
            residual[(size_t)m * H_ + lane] = rb + rw0 * v0 + rw1 * v1 + rw2 * v2 + rw3 * v3;
        }
    }
    // stage W1 [64x64]
    #pragma unroll
    for (int i = 0; i < 4; ++i) {
        int f4 = t + i * 256;
        int row = f4 >> 4, col = (f4 & 15) * 4;
        *(float4*)&Ws[row * 68 + col] = *(const float4*)&W1[row * 64 + col];
    }
    __syncthreads();

    int tx = t & 15, ty = t >> 4;
    // GEMM1: Gr = relu(Gf[32x64] @ W1 + b1)
    {
        float4 acc0 = make_float4(0.f,0.f,0.f,0.f), acc1 = make_float4(0.f,0.f,0.f,0.f);
        #pragma unroll 8
        for (int k4 = 0; k4 < 64; k4 += 4) {
            float4 A0 = *(const float4*)&Gf[ty * 68 + k4];
            float4 A1 = *(const float4*)&Gf[(ty + 16) * 68 + k4];
            float4 W0 = *(const float4*)&Ws[(k4 + 0) * 68 + 4 * tx];
            float4 W1v = *(const float4*)&Ws[(k4 + 1) * 68 + 4 * tx];
            float4 W2v = *(const float4*)&Ws[(k4 + 2) * 68 + 4 * tx];
            float4 W3v = *(const float4*)&Ws[(k4 + 3) * 68 + 4 * tx];
            fma4(acc0, A0.x, W0); fma4(acc0, A0.y, W1v); fma4(acc0, A0.z, W2v); fma4(acc0, A0.w, W3v);
            fma4(acc1, A1.x, W0); fma4(acc1, A1.y, W1v); fma4(acc1, A1.z, W2v); fma4(acc1, A1.w, W3v);
        }
        float4 bi1 = *(const float4*)&b1[4 * tx];
        #pragma unroll
        for (int r = 0; r < 2; ++r) {
            float4 a = r ? acc1 : acc0;
            float v0 = a.x + bi1.x; v0 = v0 > 0.f ? v0 : 0.f;
            float v1 = a.y + bi1.y; v1 = v1 > 0.f ? v1 : 0.f;
            float v2 = a.z + bi1.z; v2 = v2 > 0.f ? v2 : 0.f;
            float v3 = a.w + bi1.w; v3 = v3 > 0.f ? v3 : 0.f;
            *(float4*)&Gr[(ty + 16 * r) * 68 + 4 * tx] = make_float4(v0, v1, v2, v3);
        }
    }

    // GEMM2 per 64-col chunk: gate = sigmoid(Gr @ W2[:,chunk] + b2)
    for (int ch = 0; ch < 4; ++ch) {
        __syncthreads();   // GEMM1 Ws reads / prev chunk reads done
        #pragma unroll
        for (int i = 0; i < 4; ++i) {
            int f4 = t + i * 256;
            int row = f4 >> 4, col = (f4 & 15) * 4;
            *(float4*)&Ws[row * 68 + col] =
                *(const float4*)&W2[(size_t)row * 256 + ch * 64 + col];
        }
        __syncthreads();
        float4 acc0 = make_float4(0.f,0.f,0.f,0.f), acc1 = make_float4(0.f,0.f,0.f,0.f);
        #pragma unroll 8
        for (int k4 = 0; k4 < 64; k4 += 4) {
            float4 A0 = *(const float4*)&Gr[ty * 68 + k4];
            float4 A1 = *(const float4*)&Gr[(ty + 16) * 68 + k4];
            float4 W0 = *(const float4*)&Ws[(k4 + 0) * 68 + 4 * tx];
            float4 W1v = *(const float4*)&Ws[(k4 + 1) * 68 + 4 * tx];
            float4 W2v = *(const float4*)&Ws[(k4 + 2) * 68 + 4 * tx];
            float4 W3v = *(const float4*)&Ws[(k4 + 3) * 68 + 4 * tx];
            fma4(acc0, A0.x, W0); fma4(acc0, A0.y, W1v); fma4(acc0, A0.z, W2v); fma4(acc0, A0.w, W3v);
            fma4(acc1, A1.x, W0); fma4(acc1, A1.y, W1v); fma4(acc1, A1.z, W2v); fma4(acc1, A1.w, W3v);
        }
        float4 bi2 = *(const float4*)&b2[ch * 64 + 4 * tx];
        #pragma unroll
        for (int r = 0; r < 2; ++r) {
            float4 a = r ? acc1 : acc0;
            int m = m0 + ty + 16 * r;
            float g0 = 1.f / (1.f + expf(-(a.x + bi2.x)));
            float g1 = 1.f / (1.f + expf(-(a.y + bi2.y)));
            float g2 = 1.f / (1.f + expf(-(a.z + bi2.z)));
            float g3 = 1.f / (1.f + expf(-(a.w + bi2.w)));
            *(float4*)&gate[(size_t)m * 256 + ch * 64 + 4 * tx] = make_float4(g0, g1, g2, g3);
        }
    }
}

// ---------------------------------------------------------------------------
// K2: layer 1, both stacks, TWO checkpoints per dispatch (grid 1312),
// GEMMs via bf16 MFMA (B-frags prefetched from WT; zero GEMM-loop barriers).
__global__ __launch_bounds__(256, 4) void k_layer1(
    const int*   __restrict__ cnt,    // [2N]  adj rows 0..N, pea rows N..2N
    const int*   __restrict__ cols,   // [2N][NNZCAP]
    const float* __restrict__ vals,
    const ushort* __restrict__ g_init4, // [4][M][64] bf16
    int it0,
    const ushort* __restrict__ WT,    // [8][64][WPITCH] bf16 layer-0 W01^T
    const float* __restrict__ badj, const float* __restrict__ bpea,
    ushort* __restrict__ G1a4, ushort* __restrict__ G1p4)   // [2][M][256] bf16
{
    __shared__ ushort MaH[32 * WPITCH];   // 4.6 KB each
    __shared__ ushort MpH[32 * WPITCH];
    int t = threadIdx.x, lane = t & 63, w = t >> 6;
    int itk = blockIdx.x / 656;
    int lx  = blockIdx.x - itk * 656;
    int vb = (lx & 7) * 82 + (lx >> 3);   // XCD swizzle
    if (vb >= 650) return;
    int m0 = vb * 32;
    const ushort* g_init = g_init4 + (size_t)(it0 + itk) * M_ * H_;
    ushort* G1a = G1a4 + (size_t)itk * M_ * 256;
    ushort* G1p = G1p4 + (size_t)itk * M_ * 256;
    int q = lane >> 4, ml = lane & 15;
    int colg = w * 16 + ml;               // this wave-lane's output column

    // prefetch all 16 B-fragments (overlaps gather; WT is L2-resident)
    bfrag BF[8][2];
    #pragma unroll
    for (int mat = 0; mat < 8; ++mat)
        #pragma unroll
        for (int kc = 0; kc < 2; ++kc)
            BF[mat][kc] = *(const bfrag*)&WT[((size_t)mat * 64 + colg) * WPITCH + kc * 32 + q * 8];

    // ---- gather: lane=(rr,cl); rows w*8+rr and w*8+4+rr, both stacks ----
    {
        int cl = lane & 15, rr = lane >> 4;
        int mA = m0 + w * 8 + rr;
        int mB = mA + 4;
        int nA = mA % N_, nB = mB % N_;
        const ushort* gA = g_init + (size_t)(mA - nA) * H_ + cl * 4;
        const ushort* gB = g_init + (size_t)(mB - nB) * H_ + cl * 4;
        const int   *cA0 = cols + nA * NNZCAP,        *cB0 = cols + nB * NNZCAP;
        const float *vA0 = vals + nA * NNZCAP,        *vB0 = vals + nB * NNZCAP;
        const int   *cA1 = cols + (N_ + nA) * NNZCAP, *cB1 = cols + (N_ + nB) * NNZCAP;
        const float *vA1 = vals + (N_ + nA) * NNZCAP, *vB1 = vals + (N_ + nB) * NNZCAP;
        int jm = max(max(cnt[nA], cnt[nB]), max(cnt[N_ + nA], cnt[N_ + nB]));
        float4 aA0 = make_float4(0.f,0.f,0.f,0.f), aB0 = make_float4(0.f,0.f,0.f,0.f);
        float4 aA1 = make_float4(0.f,0.f,0.f,0.f), aB1 = make_float4(0.f,0.f,0.f,0.f);
        for (int j = 0; j < jm; j += 2) {     // zero-padded -> branch-free
            fma4(aA0, vA0[j],   unpack_bf4(*(const uint2*)&gA[cA0[j]   * H_]));
            fma4(aA0, vA0[j+1], unpack_bf4(*(const uint2*)&gA[cA0[j+1] * H_]));
            fma4(aB0, vB0[j],   unpack_bf4(*(const uint2*)&gB[cB0[j]   * H_]));
            fma4(aB0, vB0[j+1], unpack_bf4(*(const uint2*)&gB[cB0[j+1] * H_]));
            fma4(aA1, vA1[j],   unpack_bf4(*(const uint2*)&gA[cA1[j]   * H_]));
            fma4(aA1, vA1[j+1], unpack_bf4(*(const uint2*)&gA[cA1[j+1] * H_]));
            fma4(aB1, vB1[j],   unpack_bf4(*(const uint2*)&gB[cB1[j]   * H_]));
            fma4(aB1, vB1[j+1], unpack_bf4(*(const uint2*)&gB[cB1[j+1] * H_]));
        }
        *(uint2*)&MaH[(w * 8 + rr) * WPITCH + cl * 4]     = pack_bf4(aA0);
        *(uint2*)&MaH[(w * 8 + 4 + rr) * WPITCH + cl * 4] = pack_bf4(aB0);
        *(uint2*)&MpH[(w * 8 + rr) * WPITCH + cl * 4]     = pack_bf4(aA1);
        *(uint2*)&MpH[(w * 8 + 4 + rr) * WPITCH + cl * 4] = pack_bf4(aB1);
    }
    __syncthreads();

    // ---- 8 stages x 2 rowgroups, MFMA; C-layout col=ml, row=q*4+j ----
    #pragma unroll
    for (int sc = 0; sc < 8; ++sc) {
        int stack = sc >> 2, c = sc & 3;
        const ushort* Msrc = stack ? MpH : MaH;
        float bv = (stack ? bpea : badj)[c * L_ * H_ + colg];   // layer 0 bias
        ushort* Gout = stack ? G1p : G1a;
        #pragma unroll
        for (int r = 0; r < 2; ++r) {
            bfrag A0 = *(const bfrag*)&Msrc[(16 * r + ml) * WPITCH + q * 8];
            bfrag A1 = *(const bfrag*)&Msrc[(16 * r + ml) * WPITCH + 32 + q * 8];
            f32x4 acc = {0.f, 0.f, 0.f, 0.f};
            acc = __builtin_amdgcn_mfma_f32_16x16x32_bf16(A0, BF[sc][0], acc, 0, 0, 0);
            acc = __builtin_amdgcn_mfma_f32_16x16x32_bf16(A1, BF[sc][1], acc, 0, 0, 0);
            #pragma unroll
            for (int j = 0; j < 4; ++j) {
                float v = acc[j] + bv;
                v = v > 0.f ? v : 0.f;
                Gout[(size_t)(m0 + 16 * r + q * 4 + j) * 256 + c * 64 + colg] = bf_rne(v);
            }
        }
    }
}

// ---------------------------------------------------------------------------
// K3: layer 2 + gate mix + reduce GEMM + partial sums, all fused (R11-proven).
__global__ __launch_bounds__(256, 3) void k_mix(
    const int*   __restrict__ cnt,
    const int*   __restrict__ cols,
    const float* __restrict__ vals,
    const ushort* __restrict__ G1a, const ushort* __restrict__ G1p,  // [M][256] bf16
    const float* __restrict__ wadj, const float* __restrict__ badj,
    const float* __restrict__ wpea, const float* __restrict__ bpea,
    const float* __restrict__ gate,     // [M][256]
    const float* __restrict__ reduce_w, // [256][64]
    const float* __restrict__ reduce_b, // [64]
    const float* __restrict__ residual, // [M][64]
    float* __restrict__ cr,             // [M][64]
    float* __restrict__ partials)       // [2*650]
{
    __shared__ float Mt[32 * 260];
    __shared__ float Ws[64 * 68];
    int t = threadIdx.x, lane = t & 63, w = t >> 6;
    int vb = (blockIdx.x & 7) * 82 + (blockIdx.x >> 3);   // XCD swizzle
    if (vb >= 650) return;
    int m0 = vb * 32;
    int tx = t & 15, ty = t >> 4;

    float4 res[4][2];   // gate*relu(adj) -> then full mix, carried in regs
    float4 gsv[4][2];   // saved gate

    // ======== stack A gather: 2 rows x unroll 2, bf16 unpack ========
    for (int pp = 0; pp < 8; pp += 2) {
        int ma = m0 + w * 8 + pp, mb = ma + 1;
        int na = ma % N_, nb = mb % N_;
        const ushort* ga = G1a + (size_t)(ma - na) * 256 + lane * 4;
        const ushort* gb = G1a + (size_t)(mb - nb) * 256 + lane * 4;
        const int   *cap = cols + na * NNZCAP, *cbp = cols + nb * NNZCAP;
        const float *vap = vals + na * NNZCAP, *vbp = vals + nb * NNZCAP;
        int jm = max(cnt[na], cnt[nb]);
        float4 a0 = make_float4(0.f,0.f,0.f,0.f), a1 = make_float4(0.f,0.f,0.f,0.f);
        for (int j = 0; j < jm; j += 2) {     // zero-padded -> branch-free
            float w00 = vap[j], w01 = vap[j+1];
            float w10 = vbp[j], w11 = vbp[j+1];
            float4 x00 = unpack_bf4(*(const uint2*)&ga[cap[j]   * 256]);
            float4 x01 = unpack_bf4(*(const uint2*)&ga[cap[j+1] * 256]);
            float4 x10 = unpack_bf4(*(const uint2*)&gb[cbp[j]   * 256]);
            float4 x11 = unpack_bf4(*(const uint2*)&gb[cbp[j+1] * 256]);
            fma4(a0, w00, x00); fma4(a0, w01, x01);
            fma4(a1, w10, x10); fma4(a1, w11, x11);
        }
        *(float4*)&Mt[(w * 8 + pp) * 260 + lane * 4]     = a0;
        *(float4*)&Mt[(w * 8 + pp + 1) * 260 + lane * 4] = a1;
    }

    #pragma unroll
    for (int c = 0; c < 4; ++c) {
        __syncthreads();
        const float* w0 = wadj + (size_t)c * 16384 + 8192;   // layer 1
        const float* w1 = w0 + 4096;
        #pragma unroll
        for (int i = 0; i < 4; ++i) {
            int f4 = t + i * 256;
            int row = f4 >> 4, col = (f4 & 15) * 4;
            float4 x0 = *(const float4*)&w0[row * 64 + col];
            float4 x1 = *(const float4*)&w1[row * 64 + col];
            *(float4*)&Ws[row * 68 + col] = make_float4(x0.x + x1.x, x0.y + x1.y,
                                                        x0.z + x1.z, x0.w + x1.w);
        }
        __syncthreads();
        float4 acc0 = make_float4(0.f,0.f,0.f,0.f), acc1 = make_float4(0.f,0.f,0.f,0.f);
        #pragma unroll 8
        for (int k4 = 0; k4 < 64; k4 += 4) {
            float4 A0 = *(const float4*)&Mt[ty * 260 + c * 64 + k4];
            float4 A1 = *(const float4*)&Mt[(ty + 16) * 260 + c * 64 + k4];
            float4 W0 = *(const float4*)&Ws[(k4 + 0) * 68 + 4 * tx];
            float4 W1 = *(const float4*)&Ws[(k4 + 1) * 68 + 4 * tx];
            float4 W2 = *(const float4*)&Ws[(k4 + 2) * 68 + 4 * tx];
            float4 W3 = *(const float4*)&Ws[(k4 + 3) * 68 + 4 * tx];
            fma4(acc0, A0.x, W0); fma4(acc0, A0.y, W1); fma4(acc0, A0.z, W2); fma4(acc0, A0.w, W3);
            fma4(acc1, A1.x, W0); fma4(acc1, A1.y, W1); fma4(acc1, A1.z, W2); fma4(acc1, A1.w, W3);
        }
        float4 bA = *(const float4*)&badj[(c * L_ + 1) * H_ + 4 * tx];
        #pragma unroll
        for (int r = 0; r < 2; ++r) {
            float4 a = r ? acc1 : acc0;
            float v0 = a.x + bA.x; v0 = v0 > 0.f ? v0 : 0.f;
            float v1 = a.y + bA.y; v1 = v1 > 0.f ? v1 : 0.f;
            float v2 = a.z + bA.z; v2 = v2 > 0.f ? v2 : 0.f;
            float v3 = a.w + bA.w; v3 = v3 > 0.f ? v3 : 0.f;
            size_t o = (size_t)(m0 + ty + 16 * r) * 256 + c * 64 + 4 * tx;
            float4 g = *(const float4*)&gate[o];
            gsv[c][r] = g;
            res[c][r] = make_float4(g.x * v0, g.y * v1, g.z * v2, g.w * v3);
        }
    }

    // ======== stack P: re-gather, mix into registers, commit to Mt ========
    __syncthreads();   // all Mt reads done before overwrite
    for (int pp = 0; pp < 8; pp += 2) {
        int ma = m0 + w * 8 + pp, mb = ma + 1;
        int na = ma % N_, nb = mb % N_;
        const ushort* ga = G1p + (size_t)(ma - na) * 256 + lane * 4;
        const ushort* gb = G1p + (size_t)(mb - nb) * 256 + lane * 4;
        const int   *cap = cols + (N_ + na) * NNZCAP, *cbp = cols + (N_ + nb) * NNZCAP;
        const float *vap = vals + (N_ + na) * NNZCAP, *vbp = vals + (N_ + nb) * NNZCAP;
        int jm = max(cnt[N_ + na], cnt[N_ + nb]);
        float4 a0 = make_float4(0.f,0.f,0.f,0.f), a1 = make_float4(0.f,0.f,0.f,0.f);
        for (int j = 0; j < jm; j += 2) {
            float w00 = vap[j], w01 = vap[j+1];
            float w10 = vbp[j], w11 = vbp[j+1];
            float4 x00 = unpack_bf4(*(const uint2*)&ga[cap[j]   * 256]);
            float4 x01 = unpack_bf4(*(const uint2*)&ga[cap[j+1] * 256]);
            float4 x10 = unpack_bf4(*(const uint2*)&gb[cbp[j]   * 256]);
            float4 x11 = unpack_bf4(*(const uint2*)&gb[cbp[j+1] * 256]);
            fma4(a0, w00, x00); fma4(a0, w01, x01);
            fma4(a1, w10, x10); fma4(a1, w11, x11);
        }
        *(float4*)&Mt[(w * 8 + pp) * 260 + lane * 4]     = a0;
        *(float4*)&Mt[(w * 8 + pp + 1) * 260 + lane * 4] = a1;
    }

    #pragma unroll
    for (int c = 0; c < 4; ++c) {
        __syncthreads();   // prev GEMM's slice reads done -> safe to commit c-1
        if (c > 0) {
            *(float4*)&Mt[ty * 260 + (c - 1) * 64 + 4 * tx]        = res[c - 1][0];
            *(float4*)&Mt[(ty + 16) * 260 + (c - 1) * 64 + 4 * tx] = res[c - 1][1];
        }
        const float* w0 = wpea + (size_t)c * 16384 + 8192;   // layer 1
        const float* w1 = w0 + 4096;
        #pragma unroll
        for (int i = 0; i < 4; ++i) {
            int f4 = t + i * 256;
            int row = f4 >> 4, col = (f4 & 15) * 4;
            float4 x0 = *(const float4*)&w0[row * 64 + col];
            float4 x1 = *(const float4*)&w1[row * 64 + col];
            *(float4*)&Ws[row * 68 + col] = make_float4(x0.x + x1.x, x0.y + x1.y,
                                                        x0.z + x1.z, x0.w + x1.w);
        }
        __syncthreads();
        float4 acc0 = make_float4(0.f,0.f,0.f,0.f), acc1 = make_float4(0.f,0.f,0.f,0.f);
        #pragma unroll 8
        for (int k4 = 0; k4 < 64; k4 += 4) {
            float4 A0 = *(const float4*)&Mt[ty * 260 + c * 64 + k4];
            float4 A1 = *(const float4*)&Mt[(ty + 16) * 260 + c * 64 + k4];
            float4 W0 = *(const float4*)&Ws[(k4 + 0) * 68 + 4 * tx];
            float4 W1 = *(const float4*)&Ws[(k4 + 1) * 68 + 4 * tx];
            float4 W2 = *(const float4*)&Ws[(k4 + 2) * 68 + 4 * tx];
            float4 W3 = *(const float4*)&Ws[(k4 + 3) * 68 + 4 * tx];
            fma4(acc0, A0.x, W0); fma4(acc0, A0.y, W1); fma4(acc0, A0.z, W2); fma4(acc0, A0.w, W3);
            fma4(acc1, A1.x, W0); fma4(acc1, A1.y, W1); fma4(acc1, A1.z, W2); fma4(acc1, A1.w, W3);
        }
        float4 bP = *(const float4*)&bpea[(c * L_ + 1) * H_ + 4 * tx];
        #pragma unroll
        for (int r = 0; r < 2; ++r) {
            float4 p = r ? acc1 : acc0;
            float v0 = p.x + bP.x; v0 = v0 > 0.f ? v0 : 0.f;
            float v1 = p.y + bP.y; v1 = v1 > 0.f ? v1 : 0.f;
            float v2 = p.z + bP.z; v2 = v2 > 0.f ? v2 : 0.f;
            float v3 = p.w + bP.w; v3 = v3 > 0.f ? v3 : 0.f;
            float4 g  = gsv[c][r];
            float4 rr = res[c][r];
            res[c][r] = make_float4(rr.x + (1.f - g.x) * v0,
                                    rr.y + (1.f - g.y) * v1,
                                    rr.z + (1.f - g.z) * v2,
                                    rr.w + (1.f - g.w) * v3);
        }
    }
    __syncthreads();   // last GEMM's slice-3 reads done
    *(float4*)&Mt[ty * 260 + 3 * 64 + 4 * tx]        = res[3][0];
    *(float4*)&Mt[(ty + 16) * 260 + 3 * 64 + 4 * tx] = res[3][1];

    // ======== reduce GEMM: cr = Mt[32x256] @ reduce_w + bias + residual ======
    float4 racc0 = make_float4(0.f,0.f,0.f,0.f), racc1 = make_float4(0.f,0.f,0.f,0.f);
    for (int kk = 0; kk < 4; ++kk) {
        __syncthreads();   // Mt commits visible (kk=0) / prev Ws reads done
        #pragma unroll
        for (int i = 0; i < 4; ++i) {
            int f4 = t + i * 256;
            int row = f4 >> 4, col = (f4 & 15) * 4;
            *(float4*)&Ws[row * 68 + col] =
                *(const float4*)&reduce_w[(size_t)(kk * 64 + row) * 64 + col];
        }
        __syncthreads();
        #pragma unroll 8
        for (int k4 = 0; k4 < 64; k4 += 4) {
            float4 A0 = *(const float4*)&Mt[ty * 260 + kk * 64 + k4];
            float4 A1 = *(const float4*)&Mt[(ty + 16) * 260 + kk * 64 + k4];
            float4 W0 = *(const float4*)&Ws[(k4 + 0) * 68 + 4 * tx];
            float4 W1 = *(const float4*)&Ws[(k4 + 1) * 68 + 4 * tx];
            float4 W2 = *(const float4*)&Ws[(k4 + 2) * 68 + 4 * tx];
            float4 W3 = *(const float4*)&Ws[(k4 + 3) * 68 + 4 * tx];
            fma4(racc0, A0.x, W0); fma4(racc0, A0.y, W1); fma4(racc0, A0.z, W2); fma4(racc0, A0.w, W3);
            fma4(racc1, A1.x, W0); fma4(racc1, A1.y, W1); fma4(racc1, A1.z, W2); fma4(racc1, A1.w, W3);
        }
    }
    float4 bi = *(const float4*)&reduce_b[4 * tx];
    float s = 0.f, s2 = 0.f;
    #pragma unroll
    for (int r = 0; r < 2; ++r) {
        int m = m0 + ty + 16 * r;
        float4 a = r ? racc1 : racc0;
        float4 rv = *(const float4*)&residual[(size_t)m * 64 + 4 * tx];
        float v0 = a.x + bi.x + rv.x;
        float v1 = a.y + bi.y + rv.y;
        float v2 = a.z + bi.z + rv.z;
        float v3 = a.w + bi.w + rv.w;
        *(float4*)&cr[(size_t)m * 64 + 4 * tx] = make_float4(v0, v1, v2, v3);
        s += v0 + v1 + v2 + v3;
        s2 += v0 * v0 + v1 * v1 + v2 * v2 + v3 * v3;
    }
    __syncthreads();   // Ws reads done; reuse as reduction scratch
    float* r1 = Ws;
    float* r2 = Ws + 256;
    r1[t] = s; r2[t] = s2;
    __syncthreads();
    for (int off = 128; off > 0; off >>= 1) {
        if (t < off) { r1[t] += r1[t + off]; r2[t] += r2[t + off]; }
        __syncthreads();
    }
    if (t == 0) { partials[vb] = r1[0]; partials[650 + vb] = r2[0]; }
}

// ---------------------------------------------------------------------------
// K5: out = relu(ocw*norm(cr) + ocb) @ olw + olb. One wave per 64 rows.
__global__ __launch_bounds__(64) void k_out(
    const float* __restrict__ cr, const float* __restrict__ partials,
    const float* __restrict__ ocw, const float* __restrict__ ocb,
    const float* __restrict__ olw, const float* __restrict__ olb,
    float* __restrict__ out) {
    int t = threadIdx.x;
    float a = 0.f, b2s = 0.f;
    for (int i = t; i < 650; i += 64) { a += partials[i]; b2s += partials[650 + i]; }
    #pragma unroll
    for (int off = 32; off > 0; off >>= 1) {
        a   += __shfl_xor(a, off);
        b2s += __shfl_xor(b2s, off);
    }
    const float inv = 1.f / (float)(M_ * H_);
    float mu  = a * inv;
    float var = b2s * inv - mu * mu;
    float rs  = rsqrtf(var + 1e-5f);

    int m = blockIdx.x * 64 + t;          // M = 325*64 exactly
    int b = m / N_, n = m % N_;
    float cw[P_], cb[P_], acc[P_];
    #pragma unroll
    for (int p = 0; p < P_; ++p) { cw[p] = ocw[p]; cb[p] = ocb[p]; acc[p] = 0.f; }
    const float* lr = cr + (size_t)m * H_;
    for (int h4 = 0; h4 < 64; h4 += 4) {
        float4 lv4 = *(const float4*)&lr[h4];
        float4 wv4 = *(const float4*)&olw[h4];
        float lv[4] = {(lv4.x - mu) * rs, (lv4.y - mu) * rs,
                       (lv4.z - mu) * rs, (lv4.w - mu) * rs};
        float wv[4] = {wv4.x, wv4.y, wv4.z, wv4.w};
        #pragma unroll
        for (int e = 0; e < 4; ++e) {
            float lvv = lv[e], wvv = wv[e];
            #pragma unroll
            for (int p = 0; p < P_; ++p) {
                float u = cw[p] * lvv + cb[p];
                u = u > 0.f ? u : 0.f;
                acc[p] += u * wvv;
            }
        }
    }
    float ob = olb[0];
    #pragma unroll
    for (int p = 0; p < P_; ++p)
        out[(size_t)(b * P_ + p) * N_ + n] = acc[p] + ob;
}

// ---------------------------------------------------------------------------
extern "C" void kernel_launch(void* const* d_in, const int* in_sizes, int n_in,
                              void* d_out, int out_size, void* d_ws, size_t ws_size,
                              hipStream_t stream) {
    const float* inp      = (const float*)d_in[0];
    const float* adj_fwd  = (const float*)d_in[1];
    const float* pea_fwd  = (const float*)d_in[3];
    const float* w_in     = (const float*)d_in[5];
    const float* b_in     = (const float*)d_in[6];
    const float* res_w    = (const float*)d_in[7];
    const float* res_b    = (const float*)d_in[8];
    const float* gconv_w  = (const float*)d_in[9];
    const float* gconv_b  = (const float*)d_in[10];
    const float* gate1_w  = (const float*)d_in[11];
    const float* gate1_b  = (const float*)d_in[12];
    const float* gate2_w  = (const float*)d_in[13];
    const float* gate2_b  = (const float*)d_in[14];
    const float* reduce_w = (const float*)d_in[15];
    const float* reduce_b = (const float*)d_in[16];
    const float* gadj_w   = (const float*)d_in[17];
    const float* gadj_b   = (const float*)d_in[18];
    const float* gpea_w   = (const float*)d_in[19];
    const float* gpea_b   = (const float*)d_in[20];
    const float* ocw      = (const float*)d_in[21];
    const float* ocb      = (const float*)d_in[22];
    const float* olw      = (const float*)d_in[23];
    const float* olb      = (const float*)d_in[24];
    float* out = (float*)d_out;

    // workspace layout — fp32 region then bf16 buffers (~86 MB total)
    float* ws       = (float*)d_ws;
    float* gate     = ws;                              // M*256
    float* residual = gate + (size_t)M_ * 256;         // M*64
    float* cr       = residual + (size_t)M_ * H_;      // M*64
    float* partials = cr + (size_t)M_ * H_;            // 1300
    int*   scnt  = (int*)(partials + 1300);            // 2*325
    int*   scols = scnt + 2 * N_;                      // 2*325*64
    float* svals = (float*)(scols + 2 * N_ * NNZCAP);  // 2*325*64
    ushort* G1a4 = (ushort*)(svals + 2 * N_ * NNZCAP); // 2 slots x M*256 bf16
    ushort* G1p4 = G1a4 + 2 * (size_t)M_ * 256;        // 2 slots x M*256 bf16
    ushort* g_init4 = G1p4 + 2 * (size_t)M_ * 256;     // 4 x M*64 bf16
    ushort* WT   = g_init4 + 4 * (size_t)M_ * H_;      // 8*64*WPITCH

    k_build_sparse<<<N_, 64, 0, stream>>>(adj_fwd, scnt,      scols,              svals);
    k_build_sparse<<<N_, 64, 0, stream>>>(pea_fwd, scnt + N_, scols + N_*NNZCAP,  svals + N_*NNZCAP);
    k_ginit<<<(4 * M_ * H_) / 256, 256, 0, stream>>>(inp, w_in, b_in, g_init4);
    k_prep_w<<<8, 256, 0, stream>>>(gadj_w, gpea_w, WT);

    for (int half = 0; half < 2; ++half) {
        // layer 1 for checkpoints {2*half, 2*half+1} in one batched dispatch
        k_layer1<<<2 * 656, 256, 0, stream>>>(
            scnt, scols, svals, g_init4, half * 2,
            WT, gadj_b, gpea_b, G1a4, G1p4);
        for (int it = half * 2; it < half * 2 + 2; ++it) {
            k_gate<<<M_ / 32, 256, 0, stream>>>(
                inp, w_in, b_in, gconv_w, gconv_b, res_w, res_b, cr, partials, it,
                gate1_w, gate1_b, gate2_w, gate2_b, residual, gate);
            int slot = it & 1;
            k_mix<<<656, 256, 0, stream>>>(
                scnt, scols, svals,
                G1a4 + (size_t)slot * M_ * 256, G1p4 + (size_t)slot * M_ * 256,
                gadj_w, gadj_b, gpea_w, gpea_b, gate,
                reduce_w, reduce_b, residual, cr, partials);
        }
    }

    k_out<<<N_, 64, 0, stream>>>(cr, partials, ocw, ocb, olw, olb, out);
}